// Round 11
// baseline (157.318 us; speedup 1.0000x reference)
//
#include <hip/hip_runtime.h>
#include <hip/hip_bf16.h>
#include <hip/hip_fp16.h>
#include <cstddef>

// ---------------------------------------------------------------------------
// GAT 2-layer forward. N=50000 nodes, E=800000 edges (+N self loops).
// R11: 4 launches. agg1+gemm2 fused (GEMM is row-local): block owns a
//      64-node tile, aggregates into the MFMA A-tile in LDS (stride 72),
//      then MFMA layer-2 directly — no xr2h round-trip.
// ---------------------------------------------------------------------------

#define NNODES 50000
#define NEDGES 800000
#define FOUT   64
#define NBKT   512
#define BSPAN  98       // nodes per bucket (512*98 = 50176 >= 50000)
#define CHUNK  4096     // edges per localsort block
#define REGS   2560     // csrc region stride per bucket (cap; mean ~1666)
#define NLBMAX 256      // >= number of localsort blocks (196)

__device__ __forceinline__ float leaky(float t) { return t > 0.f ? t : 0.2f * t; }
#define RL(v, j) __builtin_amdgcn_readlane((v), (j))

using half8  = __attribute__((ext_vector_type(8))) _Float16;
using half4v = __attribute__((ext_vector_type(4))) _Float16;
using f32x4  = __attribute__((ext_vector_type(4))) float;

// ---------------- stage 1: local counting sort by coarse bucket ------------

__global__ __launch_bounds__(256) void k_localsort(
    const int* __restrict__ ei, unsigned* __restrict__ gout,
    int* __restrict__ goff, int E)
{
    __shared__ unsigned lrec[CHUNK];   // s | d<<16 (both < 2^16)
    __shared__ unsigned lsrt[CHUNK];
    __shared__ int cnt[NBKT];
    __shared__ int cur[NBKT];
    __shared__ int exc[NBKT + 1];

    const int t = threadIdx.x;
    const int blk = blockIdx.x;
    const int e0 = blk * CHUNK;
    const int e1 = min(e0 + CHUNK, E);
    const int ne = e1 - e0;

    for (int i = t; i < NBKT; i += 256) cnt[i] = 0;
    __syncthreads();

    for (int i = e0 + t; i < e1; i += 256) {
        unsigned s = (unsigned)ei[i];
        unsigned d = (unsigned)ei[E + i];
        lrec[i - e0] = s | (d << 16);
        atomicAdd(&cnt[d / BSPAN], 1);
    }
    __syncthreads();

    // exclusive scan of cnt[512] by wave 0 (lane covers 8 bins)
    if (t < 64) {
        int c[8]; int s = 0;
        #pragma unroll
        for (int k = 0; k < 8; ++k) { c[k] = cnt[t * 8 + k]; s += c[k]; }
        int inc = s;
        #pragma unroll
        for (int d = 1; d < 64; d <<= 1) { int u = __shfl_up(inc, d); if (t >= d) inc += u; }
        int ex = inc - s;
        #pragma unroll
        for (int k = 0; k < 8; ++k) { exc[t * 8 + k] = ex; cur[t * 8 + k] = ex; ex += c[k]; }
        if (t == 63) exc[NBKT] = ex;
    }
    __syncthreads();

    for (int i = t; i < ne; i += 256) {
        unsigned r = lrec[i];
        unsigned d = r >> 16;
        unsigned b = d / BSPAN;
        int p = atomicAdd(&cur[b], 1);
        lsrt[p] = (r & 0xFFFFu) | ((d - b * BSPAN) << 16);
    }
    __syncthreads();

    for (int i = t; i < ne; i += 256) gout[e0 + i] = lsrt[i];       // coalesced
    for (int i = t; i < NBKT + 1; i += 256)
        goff[blk * (NBKT + 1) + i] = e0 + exc[i];
}

// ---------------- per-bucket exact CSR (device body, dynamic LDS) ----------

__device__ __forceinline__ void csr_body(
    char* smem, int bkt,
    const unsigned* __restrict__ gout, const int* __restrict__ goff,
    int* __restrict__ csrc, int2* __restrict__ rowse,
    int n, int nlb)
{
    unsigned* ltmp  = (unsigned*)smem;                          // REGS
    int* lout  = (int*)(smem + REGS * 4);                       // REGS
    int* lcnt  = (int*)(smem + 2 * REGS * 4);                   // BSPAN
    int* lbase = lcnt + BSPAN;                                  // BSPAN+1
    int* lcur  = lbase + BSPAN + 1;                             // BSPAN
    int* rg0   = lcur + BSPAN;                                  // NLBMAX
    int* rlen  = rg0 + NLBMAX;                                  // NLBMAX
    int* rbase = rlen + NLBMAX;                                 // NLBMAX+1

    const int t = threadIdx.x;
    const int node0 = bkt * BSPAN;
    if (node0 >= n) return;
    const int nn = min(BSPAN, n - node0);

    for (int i = t; i < BSPAN; i += 256) lcnt[i] = (i < nn) ? 1 : 0;  // self loop
    if (t < nlb) {
        int g0 = goff[t * (NBKT + 1) + bkt];
        int g1 = goff[t * (NBKT + 1) + bkt + 1];
        rg0[t] = g0;
        rlen[t] = g1 - g0;
    }
    __syncthreads();

    // exclusive scan of rlen[nlb<=256] by wave 0 (lane covers 4 entries)
    if (t < 64) {
        int c[4]; int s = 0;
        #pragma unroll
        for (int k = 0; k < 4; ++k) {
            int idx = t * 4 + k;
            c[k] = (idx < nlb) ? rlen[idx] : 0;
            s += c[k];
        }
        int inc = s;
        #pragma unroll
        for (int d = 1; d < 64; d <<= 1) { int u = __shfl_up(inc, d); if (t >= d) inc += u; }
        int ex = inc - s;
        #pragma unroll
        for (int k = 0; k < 4; ++k) { rbase[t * 4 + k] = ex; ex += c[k]; }
        if (t == 63) rbase[NLBMAX] = ex;
    }
    __syncthreads();

    const int tot = min(rbase[nlb], REGS - BSPAN);

    // thread-per-record gather: binary search run, copy
    for (int i = t; i < tot; i += 256) {
        int lo = 0, hi = nlb;
        while (hi - lo > 1) {
            int mid = (lo + hi) >> 1;
            if (rbase[mid] <= i) lo = mid; else hi = mid;
        }
        ltmp[i] = gout[rg0[lo] + (i - rbase[lo])];
    }
    __syncthreads();

    for (int i = t; i < tot; i += 256) atomicAdd(&lcnt[ltmp[i] >> 16], 1);
    __syncthreads();

    // exclusive scan of lcnt[98] by wave 0 (lane covers 2 bins)
    if (t < 64) {
        int b0 = t * 2, b1 = t * 2 + 1;
        int c0 = (b0 < BSPAN) ? lcnt[b0] : 0;
        int c1 = (b1 < BSPAN) ? lcnt[b1] : 0;
        int s = c0 + c1;
        int inc = s;
        #pragma unroll
        for (int d = 1; d < 64; d <<= 1) { int u = __shfl_up(inc, d); if (t >= d) inc += u; }
        int ex = inc - s;
        if (b0 < BSPAN) { lbase[b0] = ex;      lcur[b0] = ex + 1; }      // slot 0 = self
        if (b1 < BSPAN) { lbase[b1] = ex + c0; lcur[b1] = ex + c0 + 1; }
        if (t == 63) lbase[BSPAN] = inc;
    }
    __syncthreads();

    for (int i = t; i < nn; i += 256) lout[lbase[i]] = node0 + i;    // self loops
    for (int i = t; i < tot; i += 256) {
        unsigned r = ltmp[i];
        int p = atomicAdd(&lcur[r >> 16], 1);
        lout[p] = (int)(r & 0xFFFFu);
    }
    __syncthreads();

    const int gbase = bkt * REGS;
    const int total = tot + nn;
    for (int i = t; i < total; i += 256) csrc[gbase + i] = lout[i];  // coalesced
    for (int i = t; i < nn; i += 256)
        rowse[node0 + i] = make_int2(gbase + lbase[i], gbase + lbase[i + 1]);
}

// ---------------- MFMA GEMM + alpha (device body, dynamic LDS) -------------
// Block = 64 rows x 64 cols, 4 waves; wave w owns rows [w*16, w*16+16).
// A-frag: A[m=lane&15][k=quad*8+j]; C/D: col=lane&15, row=quad*4+reg.

template <int K, typename XT>
__device__ __forceinline__ void gemm_body(
    char* smem, int bx,
    const XT* __restrict__ x, const float* __restrict__ W,
    const float* __restrict__ a_src, const float* __restrict__ a_dst,
    __half* __restrict__ h16, float* __restrict__ as_, float* __restrict__ ad_, int n)
{
    constexpr int KP = K + 8;                 // row stride in halves; 2*KP % 16 == 0
    _Float16* Ah = (_Float16*)smem;           // 64 * KP
    _Float16* Wf = (_Float16*)(smem + 64 * KP * 2);  // K * 64, fragment layout

    const int t    = threadIdx.x;
    const int lane = t & 63;
    const int wv   = t >> 6;
    const int n16  = lane & 15;
    const int quad = lane >> 4;
    const int r0   = bx * 64;

    // stage W in B-fragment layout: Wf[((k>>3)*64 + c)*8 + (k&7)]
    for (int i = t; i < K * 64; i += 256) {
        int k = i >> 6, c = i & 63;
        Wf[((k >> 3) * 64 + c) * 8 + (k & 7)] = (_Float16)W[i];
    }
    // stage x rows as fp16
    if constexpr (sizeof(XT) == 4) {
        constexpr int KQ = K / 4;
        for (int i = t; i < 64 * KQ; i += 256) {
            int r = i / KQ, kq = i % KQ;
            int row = r0 + r;
            float4 v = make_float4(0.f, 0.f, 0.f, 0.f);
            if (row < n) v = ((const float4*)(x + (size_t)row * K))[kq];
            half4v hv = { (_Float16)v.x, (_Float16)v.y, (_Float16)v.z, (_Float16)v.w };
            *(half4v*)&Ah[r * KP + kq * 4] = hv;
        }
    } else {
        constexpr int KO = K / 8;
        for (int i = t; i < 64 * KO; i += 256) {
            int r = i / KO, ko = i % KO;
            int row = r0 + r;
            half8 hv = {};
            if (row < n) hv = *(const half8*)((const _Float16*)x + (size_t)row * K + ko * 8);
            *(half8*)&Ah[r * KP + ko * 8] = hv;
        }
    }
    __syncthreads();

    // preload all B fragments (block-uniform W)
    half8 bfr[K / 32][4];
    #pragma unroll
    for (int kk = 0; kk < K / 32; ++kk)
        #pragma unroll
        for (int ct = 0; ct < 4; ++ct)
            bfr[kk][ct] = *(const half8*)&Wf[((kk * 4 + quad) * 64 + ct * 16 + n16) * 8];

    f32x4 acc[4];
    #pragma unroll
    for (int ct = 0; ct < 4; ++ct) acc[ct] = (f32x4){0.f, 0.f, 0.f, 0.f};

    #pragma unroll
    for (int kk = 0; kk < K / 32; ++kk) {
        half8 a = *(const half8*)&Ah[(wv * 16 + n16) * KP + kk * 32 + quad * 8];
        #pragma unroll
        for (int ct = 0; ct < 4; ++ct)
            acc[ct] = __builtin_amdgcn_mfma_f32_16x16x32_f16(a, bfr[kk][ct], acc[ct], 0, 0, 0);
    }

    // epilogue: alpha dots off fp32 accumulators + fp16 h store
    const int rowb = r0 + wv * 16 + quad * 4;
    float asv[4], adv[4];
    #pragma unroll
    for (int ct = 0; ct < 4; ++ct) {
        asv[ct] = a_src[ct * 16 + n16];
        adv[ct] = a_dst[ct * 16 + n16];
    }
    float pa[4] = {0.f, 0.f, 0.f, 0.f}, pd[4] = {0.f, 0.f, 0.f, 0.f};
    #pragma unroll
    for (int ct = 0; ct < 4; ++ct)
        #pragma unroll
        for (int r = 0; r < 4; ++r) {
            pa[r] = fmaf(acc[ct][r], asv[ct], pa[r]);
            pd[r] = fmaf(acc[ct][r], adv[ct], pd[r]);
        }
    #pragma unroll
    for (int r = 0; r < 4; ++r) {
        #pragma unroll
        for (int d = 1; d <= 8; d <<= 1) {
            pa[r] += __shfl_xor(pa[r], d);
            pd[r] += __shfl_xor(pd[r], d);
        }
    }
    if (n16 == 0) {
        #pragma unroll
        for (int r = 0; r < 4; ++r) {
            if (rowb + r < n) { as_[rowb + r] = pa[r]; ad_[rowb + r] = pd[r]; }
        }
    }

    _Float16* hh = (_Float16*)h16;
    #pragma unroll
    for (int r = 0; r < 4; ++r) {
        if (rowb + r < n) {
            #pragma unroll
            for (int ct = 0; ct < 4; ++ct)
                hh[(size_t)(rowb + r) * 64 + ct * 16 + n16] = (_Float16)acc[ct][r];
        }
    }
}

// ---------------- fused launch 2: [csr buckets | gemm layer 1] -------------

__global__ __launch_bounds__(256) void k_csr_gemm1(
    const unsigned* __restrict__ gout, const int* __restrict__ goff,
    int* __restrict__ csrc, int2* __restrict__ rowse, int nlb,
    const float* __restrict__ x, const float* __restrict__ W1,
    const float* __restrict__ a1s, const float* __restrict__ a1d,
    __half* __restrict__ h16, float* __restrict__ as_, float* __restrict__ ad_, int n)
{
    extern __shared__ __align__(16) char smem[];
    if (blockIdx.x < NBKT)
        csr_body(smem, blockIdx.x, gout, goff, csrc, rowse, n, nlb);
    else
        gemm_body<128, float>(smem, blockIdx.x - NBKT, x, W1, a1s, a1d, h16, as_, ad_, n);
}

// ---------------- fused launch 3: agg layer-1 -> MFMA layer-2 --------------
// Block owns 64 nodes. 4 waves x 2 nodes x 8 iters aggregate into the MFMA
// A-tile in LDS (fp16, stride 72), then v_mfma layer-2 + alpha epilogue.

__global__ __launch_bounds__(256) void k_agg1_gemm2(
    const int2* __restrict__ rowse, const int* __restrict__ csrc,
    const __half* __restrict__ h16, const float* __restrict__ as_,
    const float* __restrict__ ad_, const float* __restrict__ b1,
    const float* __restrict__ W2, const float* __restrict__ a2s,
    const float* __restrict__ a2d,
    __half* __restrict__ h16b, float* __restrict__ as2_, float* __restrict__ ad2_, int n)
{
    constexpr int KP = 72;                       // 64 + 8 pad (halves)
    __shared__ __align__(16) _Float16 Ah[64 * KP];   // the MFMA A-tile
    __shared__ __align__(16) _Float16 Wf[64 * 64];
    __shared__ int2 swL[4][64];

    const int t    = threadIdx.x;
    const int lane = t & 63;
    const int wid  = t >> 6;
    const int nt0  = blockIdx.x * 64;

    // stage W2 fragments (independent of the aggregate phase)
    for (int i = t; i < 64 * 64; i += 256) {
        int k = i >> 6, c = i & 63;
        Wf[((k >> 3) * 64 + c) * 8 + (k & 7)] = (_Float16)W2[i];
    }
    // zero A-tile only when the tile is partial (last block)
    if (nt0 + 64 > n) {
        for (int i = t; i < 64 * KP; i += 256) Ah[i] = (_Float16)0.f;
        __syncthreads();
    }

    // ---- aggregate phase: 8 iterations, pair of nodes per wave ----
    for (int it = 0; it < 8; ++it) {
        const int nodeA = nt0 + (it * 4 + wid) * 2;
        if (nodeA >= n) break;

        const int half = lane >> 5;
        const int hl   = lane & 31;
        const int node = nodeA + half;
        const int ln   = node - nt0;             // local row

        const int2 se = rowse[node];
        const float adn = ad_[node];
        const int start = se.x;
        const int deg   = se.y - se.x;
        const int mdeg  = max(deg, __shfl_xor(deg, 32));

        if (mdeg <= 32) {
            int s = 0;
            const bool act = hl < deg;
            if (act) s = csrc[start + hl];
            swL[wid][lane].x = s << 6;

            const int g  = (lane >> 3) & 3;
            const int fl = (lane & 7) << 3;
            const __half* __restrict__ hf = h16 + fl;
            int nit = (deg + 3) >> 2;
            nit = max(nit, __shfl_xor(nit, 32));

            const int sbase = (half << 5) + g;
            uint4 v[8];
            #pragma unroll
            for (int j = 0; j < 8; ++j) {
                if (j < nit)
                    v[j] = *(const uint4*)(hf + swL[wid][sbase + (j << 2)].x);
            }

            float e = -1e30f;
            if (act) e = leaky(as_[s] + adn);
            float w = __expf(e);
            float dsum = w;
            #pragma unroll
            for (int d = 16; d >= 1; d >>= 1) dsum += __shfl_xor(dsum, d);
            swL[wid][lane].y = __float_as_int(w);

            float af[8] = {0.f, 0.f, 0.f, 0.f, 0.f, 0.f, 0.f, 0.f};
            #pragma unroll
            for (int j = 0; j < 8; ++j) {
                if (j < nit) {
                    float wj = __int_as_float(swL[wid][sbase + (j << 2)].y);
                    unsigned uu[4] = {v[j].x, v[j].y, v[j].z, v[j].w};
                    #pragma unroll
                    for (int q = 0; q < 4; ++q) {
                        __half2 h2 = *(__half2*)&uu[q];
                        float2 f2 = __half22float2(h2);
                        af[2 * q]     = fmaf(wj, f2.x, af[2 * q]);
                        af[2 * q + 1] = fmaf(wj, f2.y, af[2 * q + 1]);
                    }
                }
            }
            #pragma unroll
            for (int q = 0; q < 8; ++q) {
                af[q] += __shfl_xor(af[q], 8);
                af[q] += __shfl_xor(af[q], 16);
            }
            if (g == 0) {                        // relu(o) -> fp16 A-tile row
                float inv = 1.f / dsum;
                float4 b0 = *(const float4*)(b1 + fl);
                float4 b4 = *(const float4*)(b1 + fl + 4);
                float o[8] = { fmaf(af[0], inv, b0.x), fmaf(af[1], inv, b0.y),
                               fmaf(af[2], inv, b0.z), fmaf(af[3], inv, b0.w),
                               fmaf(af[4], inv, b4.x), fmaf(af[5], inv, b4.y),
                               fmaf(af[6], inv, b4.z), fmaf(af[7], inv, b4.w) };
                #pragma unroll
                for (int q = 0; q < 8; ++q) o[q] = fmaxf(o[q], 0.f);
                __half2 p0 = __floats2half2_rn(o[0], o[1]);
                __half2 p1 = __floats2half2_rn(o[2], o[3]);
                __half2 p2 = __floats2half2_rn(o[4], o[5]);
                __half2 p3 = __floats2half2_rn(o[6], o[7]);
                uint4 pk = { *(unsigned*)&p0, *(unsigned*)&p1, *(unsigned*)&p2, *(unsigned*)&p3 };
                *(uint4*)&Ah[ln * KP + fl] = pk;
            }
        } else {
            // whole-wave per node, sequentially; LDS row destination
            #pragma unroll
            for (int which = 0; which < 2; ++which) {
                const int nd = nodeA + which;
                const int lr = nd - nt0;
                const int2 se2 = rowse[nd];
                const int st = se2.x, en = se2.y;
                const float adn2 = ad_[nd];
                const __half* __restrict__ hp = h16 + lane;

                float m = -1e30f;
                for (int base = st; base < en; base += 64) {
                    int idx = base + lane;
                    if (idx < en) m = fmaxf(m, leaky(as_[csrc[idx]] + adn2));
                }
                #pragma unroll
                for (int d = 32; d >= 1; d >>= 1) m = fmaxf(m, __shfl_xor(m, d));

                float a0 = 0.f, a1 = 0.f, a2 = 0.f, a3 = 0.f, dsum = 0.f;
                for (int base = st; base < en; base += 64) {
                    int idx = base + lane;
                    int s = 0; float w = 0.f;
                    if (idx < en) {
                        s = csrc[idx];
                        w = __expf(leaky(as_[s] + adn2) - m);
                    }
                    dsum += w;
                    int off = s << 6;
                    int wu = __float_as_uint(w);
                    int cnt = min(64, en - base);
                    int cr = (cnt + 3) & ~3;
                    for (int j = 0; j < cr; j += 4) {
                        int   o0 = RL(off, j + 0), o1 = RL(off, j + 1);
                        int   o2 = RL(off, j + 2), o3 = RL(off, j + 3);
                        float w0 = __uint_as_float(RL(wu, j + 0));
                        float w1 = __uint_as_float(RL(wu, j + 1));
                        float w2 = __uint_as_float(RL(wu, j + 2));
                        float w3 = __uint_as_float(RL(wu, j + 3));
                        float v0 = __half2float(hp[o0]), v1 = __half2float(hp[o1]);
                        float v2 = __half2float(hp[o2]), v3 = __half2float(hp[o3]);
                        a0 = fmaf(w0, v0, a0);
                        a1 = fmaf(w1, v1, a1);
                        a2 = fmaf(w2, v2, a2);
                        a3 = fmaf(w3, v3, a3);
                    }
                }
                #pragma unroll
                for (int d = 32; d >= 1; d >>= 1) dsum += __shfl_xor(dsum, d);
                float o = ((a0 + a1) + (a2 + a3)) / dsum + b1[lane];
                o = fmaxf(o, 0.f);
                Ah[lr * KP + lane] = (_Float16)o;
            }
        }
    }
    __syncthreads();

    // ---- MFMA layer-2 on the LDS tile ----
    const int n16  = lane & 15;
    const int quad = lane >> 4;

    half8 bfr[2][4];
    #pragma unroll
    for (int kk = 0; kk < 2; ++kk)
        #pragma unroll
        for (int ct = 0; ct < 4; ++ct)
            bfr[kk][ct] = *(const half8*)&Wf[((kk * 4 + quad) * 64 + ct * 16 + n16) * 8];

    f32x4 acc[4];
    #pragma unroll
    for (int ct = 0; ct < 4; ++ct) acc[ct] = (f32x4){0.f, 0.f, 0.f, 0.f};

    #pragma unroll
    for (int kk = 0; kk < 2; ++kk) {
        half8 a = *(const half8*)&Ah[(wid * 16 + n16) * KP + kk * 32 + quad * 8];
        #pragma unroll
        for (int ct = 0; ct < 4; ++ct)
            acc[ct] = __builtin_amdgcn_mfma_f32_16x16x32_f16(a, bfr[kk][ct], acc[ct], 0, 0, 0);
    }

    const int rowb = nt0 + wid * 16 + quad * 4;
    float asv[4], adv[4];
    #pragma unroll
    for (int ct = 0; ct < 4; ++ct) {
        asv[ct] = a2s[ct * 16 + n16];
        adv[ct] = a2d[ct * 16 + n16];
    }
    float pa[4] = {0.f, 0.f, 0.f, 0.f}, pd[4] = {0.f, 0.f, 0.f, 0.f};
    #pragma unroll
    for (int ct = 0; ct < 4; ++ct)
        #pragma unroll
        for (int r = 0; r < 4; ++r) {
            pa[r] = fmaf(acc[ct][r], asv[ct], pa[r]);
            pd[r] = fmaf(acc[ct][r], adv[ct], pd[r]);
        }
    #pragma unroll
    for (int r = 0; r < 4; ++r) {
        #pragma unroll
        for (int d = 1; d <= 8; d <<= 1) {
            pa[r] += __shfl_xor(pa[r], d);
            pd[r] += __shfl_xor(pd[r], d);
        }
    }
    if (n16 == 0) {
        #pragma unroll
        for (int r = 0; r < 4; ++r) {
            if (rowb + r < n) { as2_[rowb + r] = pa[r]; ad2_[rowb + r] = pd[r]; }
        }
    }
    _Float16* hh = (_Float16*)h16b;
    #pragma unroll
    for (int r = 0; r < 4; ++r) {
        if (rowb + r < n) {
            #pragma unroll
            for (int ct = 0; ct < 4; ++ct)
                hh[(size_t)(rowb + r) * 64 + ct * 16 + n16] = (_Float16)acc[ct][r];
        }
    }
}

// ---------------- final aggregation (layer 2, fp32 out) --------------------

template <bool RELU, typename OT>
__device__ __forceinline__ void agg_one(
    int node, int lane, int2* __restrict__ swrow,
    const int2* __restrict__ rowse,
    const int* __restrict__ csrc, const __half* __restrict__ h16,
    const float* __restrict__ as_, const float* __restrict__ ad_,
    const float* __restrict__ bias, OT* __restrict__ out)
{
    const int2 se = rowse[node];
    const int start = se.x;
    const int end   = se.y;
    const int deg   = end - start;
    const float adn = ad_[node];

    if (deg <= 64) {
        int s = 0;
        if (lane < deg) s = csrc[start + lane];
        swrow[lane].x = s << 6;

        const int g  = lane >> 3;
        const int fl = (lane & 7) << 3;
        const __half* __restrict__ hf = h16 + fl;
        const int niter = (deg + 7) >> 3;

        uint4 v[8];
        #pragma unroll
        for (int j = 0; j < 8; ++j) {
            if (j < niter)
                v[j] = *(const uint4*)(hf + swrow[(j << 3) + g].x);
        }

        float e = -1e30f;
        if (lane < deg) e = leaky(as_[s] + adn);
        float w = __expf(e);
        float dsum = w;
        #pragma unroll
        for (int d = 32; d >= 1; d >>= 1) dsum += __shfl_xor(dsum, d);
        swrow[lane].y = __float_as_int(w);

        float af[8] = {0.f, 0.f, 0.f, 0.f, 0.f, 0.f, 0.f, 0.f};
        #pragma unroll
        for (int j = 0; j < 8; ++j) {
            if (j < niter) {
                float wj = __int_as_float(swrow[(j << 3) + g].y);
                unsigned uu[4] = {v[j].x, v[j].y, v[j].z, v[j].w};
                #pragma unroll
                for (int q = 0; q < 4; ++q) {
                    __half2 h2 = *(__half2*)&uu[q];
                    float2 f2 = __half22float2(h2);
                    af[2 * q]     = fmaf(wj, f2.x, af[2 * q]);
                    af[2 * q + 1] = fmaf(wj, f2.y, af[2 * q + 1]);
                }
            }
        }
        #pragma unroll
        for (int q = 0; q < 8; ++q) {
            af[q] += __shfl_xor(af[q], 8);
            af[q] += __shfl_xor(af[q], 16);
            af[q] += __shfl_xor(af[q], 32);
        }
        if (g == 0) {
            float inv = 1.f / dsum;
            float4 b0 = *(const float4*)(bias + fl);
            float4 b1v = *(const float4*)(bias + fl + 4);
            float o[8] = { fmaf(af[0], inv, b0.x), fmaf(af[1], inv, b0.y),
                           fmaf(af[2], inv, b0.z), fmaf(af[3], inv, b0.w),
                           fmaf(af[4], inv, b1v.x), fmaf(af[5], inv, b1v.y),
                           fmaf(af[6], inv, b1v.z), fmaf(af[7], inv, b1v.w) };
            if (RELU) {
                #pragma unroll
                for (int q = 0; q < 8; ++q) o[q] = fmaxf(o[q], 0.f);
            }
            float* op = (float*)out + (size_t)node * 64 + fl;
            *(float4*)op       = make_float4(o[0], o[1], o[2], o[3]);
            *(float4*)(op + 4) = make_float4(o[4], o[5], o[6], o[7]);
        }
    } else {
        const __half* __restrict__ hp = h16 + lane;
        float m = -1e30f;
        for (int base = start; base < end; base += 64) {
            int idx = base + lane;
            if (idx < end) m = fmaxf(m, leaky(as_[csrc[idx]] + adn));
        }
        #pragma unroll
        for (int d = 32; d >= 1; d >>= 1) m = fmaxf(m, __shfl_xor(m, d));

        float acc0 = 0.f, acc1 = 0.f, acc2 = 0.f, acc3 = 0.f, dsum = 0.f;
        for (int base = start; base < end; base += 64) {
            int idx = base + lane;
            int s = 0; float w = 0.f;
            if (idx < end) {
                s = csrc[idx];
                w = __expf(leaky(as_[s] + adn) - m);
            }
            dsum += w;
            int off = s << 6;
            int wu = __float_as_uint(w);
            int cnt = min(64, end - base);
            int cr = (cnt + 3) & ~3;
            for (int j = 0; j < cr; j += 4) {
                int   o0 = RL(off, j + 0), o1 = RL(off, j + 1);
                int   o2 = RL(off, j + 2), o3 = RL(off, j + 3);
                float w0 = __uint_as_float(RL(wu, j + 0));
                float w1 = __uint_as_float(RL(wu, j + 1));
                float w2 = __uint_as_float(RL(wu, j + 2));
                float w3 = __uint_as_float(RL(wu, j + 3));
                float v0 = __half2float(hp[o0]), v1 = __half2float(hp[o1]);
                float v2 = __half2float(hp[o2]), v3 = __half2float(hp[o3]);
                acc0 = fmaf(w0, v0, acc0);
                acc1 = fmaf(w1, v1, acc1);
                acc2 = fmaf(w2, v2, acc2);
                acc3 = fmaf(w3, v3, acc3);
            }
        }
        #pragma unroll
        for (int d = 32; d >= 1; d >>= 1) dsum += __shfl_xor(dsum, d);
        float acc = (acc0 + acc1) + (acc2 + acc3);
        float o = acc / dsum + bias[lane];
        if (RELU) o = fmaxf(o, 0.f);
        ((float*)out)[(size_t)node * 64 + lane] = o;
    }
}

template <bool RELU, typename OT>
__global__ __launch_bounds__(256) void k_aggregate(
    const int2* __restrict__ rowse,
    const int* __restrict__ csrc,
    const __half* __restrict__ h16, const float* __restrict__ as_,
    const float* __restrict__ ad_, const float* __restrict__ bias,
    OT* __restrict__ out, int n)
{
    __shared__ int2 swL[4][64];

    const int lane = threadIdx.x & 63;
    const int wid  = threadIdx.x >> 6;
    const int nodeA = (blockIdx.x * 4 + wid) * 2;
    if (nodeA >= n) return;

    const int half = lane >> 5;
    const int hl   = lane & 31;
    const int node = nodeA + half;

    const int2 se = rowse[node];
    const float adn = ad_[node];
    const int start = se.x;
    const int deg   = se.y - se.x;
    const int mdeg  = max(deg, __shfl_xor(deg, 32));

    if (mdeg <= 32) {
        int s = 0;
        const bool act = hl < deg;
        if (act) s = csrc[start + hl];
        swL[wid][lane].x = s << 6;

        const int g  = (lane >> 3) & 3;
        const int fl = (lane & 7) << 3;
        const __half* __restrict__ hf = h16 + fl;
        int nit = (deg + 3) >> 2;
        nit = max(nit, __shfl_xor(nit, 32));

        const int sbase = (half << 5) + g;
        uint4 v[8];
        #pragma unroll
        for (int j = 0; j < 8; ++j) {
            if (j < nit)
                v[j] = *(const uint4*)(hf + swL[wid][sbase + (j << 2)].x);
        }

        float e = -1e30f;
        if (act) e = leaky(as_[s] + adn);
        float w = __expf(e);
        float dsum = w;
        #pragma unroll
        for (int d = 16; d >= 1; d >>= 1) dsum += __shfl_xor(dsum, d);
        swL[wid][lane].y = __float_as_int(w);

        float af[8] = {0.f, 0.f, 0.f, 0.f, 0.f, 0.f, 0.f, 0.f};
        #pragma unroll
        for (int j = 0; j < 8; ++j) {
            if (j < nit) {
                float wj = __int_as_float(swL[wid][sbase + (j << 2)].y);
                unsigned uu[4] = {v[j].x, v[j].y, v[j].z, v[j].w};
                #pragma unroll
                for (int q = 0; q < 4; ++q) {
                    __half2 h2 = *(__half2*)&uu[q];
                    float2 f2 = __half22float2(h2);
                    af[2 * q]     = fmaf(wj, f2.x, af[2 * q]);
                    af[2 * q + 1] = fmaf(wj, f2.y, af[2 * q + 1]);
                }
            }
        }
        #pragma unroll
        for (int q = 0; q < 8; ++q) {
            af[q] += __shfl_xor(af[q], 8);
            af[q] += __shfl_xor(af[q], 16);
        }
        if (g == 0) {
            float inv = 1.f / dsum;
            float4 b0 = *(const float4*)(bias + fl);
            float4 b1v = *(const float4*)(bias + fl + 4);
            float o[8] = { fmaf(af[0], inv, b0.x), fmaf(af[1], inv, b0.y),
                           fmaf(af[2], inv, b0.z), fmaf(af[3], inv, b0.w),
                           fmaf(af[4], inv, b1v.x), fmaf(af[5], inv, b1v.y),
                           fmaf(af[6], inv, b1v.z), fmaf(af[7], inv, b1v.w) };
            if (RELU) {
                #pragma unroll
                for (int q = 0; q < 8; ++q) o[q] = fmaxf(o[q], 0.f);
            }
            float* op = (float*)out + (size_t)node * 64 + fl;
            *(float4*)op       = make_float4(o[0], o[1], o[2], o[3]);
            *(float4*)(op + 4) = make_float4(o[4], o[5], o[6], o[7]);
        }
    } else {
        agg_one<RELU, OT>(nodeA,     lane, swL[wid], rowse, csrc, h16, as_, ad_, bias, out);
        agg_one<RELU, OT>(nodeA + 1, lane, swL[wid], rowse, csrc, h16, as_, ad_, bias, out);
    }
}

// ---------------- launch ----------------

extern "C" void kernel_launch(void* const* d_in, const int* in_sizes, int n_in,
                              void* d_out, int out_size, void* d_ws, size_t ws_size,
                              hipStream_t stream) {
    const float* x   = (const float*)d_in[0];
    const int*   ei  = (const int*)  d_in[1];   // [2, E]: src row 0, dst row 1
    const float* W1  = (const float*)d_in[2];
    const float* a1s = (const float*)d_in[3];
    const float* a1d = (const float*)d_in[4];
    const float* b1  = (const float*)d_in[5];
    const float* W2  = (const float*)d_in[6];
    const float* a2s = (const float*)d_in[7];
    const float* a2d = (const float*)d_in[8];
    const float* b2  = (const float*)d_in[9];
    float* out = (float*)d_out;

    const int N_ = NNODES, E_ = NEDGES;
    const int NLB = (E_ + CHUNK - 1) / CHUNK;   // 196

    char* ws = (char*)d_ws;
    size_t off = 0;
    auto alloc = [&](size_t bytes) -> void* {
        void* p = ws + off;
        off += (bytes + 255) & ~(size_t)255;
        return p;
    };
    int*      csrc     = (int*)alloc((size_t)NBKT * REGS * 4);     // 5.24 MB
    int2*     rowse    = (int2*)alloc((size_t)N_ * 8);
    float*    as_      = (float*)alloc((size_t)N_ * 4);
    float*    ad_      = (float*)alloc((size_t)N_ * 4);
    float*    as2_     = (float*)alloc((size_t)N_ * 4);
    float*    ad2_     = (float*)alloc((size_t)N_ * 4);
    __half*   h16      = (__half*)alloc((size_t)N_ * FOUT * 2);    // 6.4 MB (layer 1)
    __half*   h16b     = (__half*)alloc((size_t)N_ * FOUT * 2);    // 6.4 MB (layer 2)
    unsigned* gout     = (unsigned*)alloc((size_t)E_ * 4);         // 3.2 MB
    int*      goff     = (int*)alloc((size_t)NLB * (NBKT + 1) * 4);

    constexpr unsigned SM_G1 = 64 * (128 + 8) * 2 + 128 * 64 * 2;  // 33792 B (>= csr carve)

    const int GB = (N_ + 63) / 64;     // 782 tiles
    const int AB = (N_ / 2 + 3) / 4;   // 6250 aggregate blocks (2 nodes/wave)

    k_localsort<<<NLB, 256, 0, stream>>>(ei, gout, goff, E_);
    k_csr_gemm1<<<NBKT + GB, 256, SM_G1, stream>>>(gout, goff, csrc, rowse, NLB,
                                                   x, W1, a1s, a1d, h16, as_, ad_, N_);
    k_agg1_gemm2<<<GB, 256, 0, stream>>>(rowse, csrc, h16, as_, ad_, b1,
                                         W2, a2s, a2d, h16b, as2_, ad2_, N_);
    k_aggregate<false, float><<<AB, 256, 0, stream>>>(rowse, csrc, h16b, as2_, ad2_, b2, out, N_);
}

// Round 12
// 157.302 us; speedup vs baseline: 1.0001x; 1.0001x over previous
//
#include <hip/hip_runtime.h>
#include <hip/hip_bf16.h>
#include <hip/hip_fp16.h>
#include <cstddef>

// ---------------------------------------------------------------------------
// GAT 2-layer forward. N=50000 nodes, E=800000 edges (+N self loops).
// R12: R11's agg1+gemm2 fusion with 512-thread blocks (8 waves): aggregate
//      phase runs 8 waves x 2 nodes x 4 iters (2x TLP, half serial depth of
//      R11); MFMA phase uses waves 0-3. deg>32 fallback __noinline__.
// ---------------------------------------------------------------------------

#define NNODES 50000
#define NEDGES 800000
#define FOUT   64
#define NBKT   512
#define BSPAN  98       // nodes per bucket (512*98 = 50176 >= 50000)
#define CHUNK  4096     // edges per localsort block
#define REGS   2560     // csrc region stride per bucket (cap; mean ~1666)
#define NLBMAX 256      // >= number of localsort blocks (196)

__device__ __forceinline__ float leaky(float t) { return t > 0.f ? t : 0.2f * t; }
#define RL(v, j) __builtin_amdgcn_readlane((v), (j))

using half8  = __attribute__((ext_vector_type(8))) _Float16;
using half4v = __attribute__((ext_vector_type(4))) _Float16;
using f32x4  = __attribute__((ext_vector_type(4))) float;

// ---------------- stage 1: local counting sort by coarse bucket ------------

__global__ __launch_bounds__(256) void k_localsort(
    const int* __restrict__ ei, unsigned* __restrict__ gout,
    int* __restrict__ goff, int E)
{
    __shared__ unsigned lrec[CHUNK];   // s | d<<16 (both < 2^16)
    __shared__ unsigned lsrt[CHUNK];
    __shared__ int cnt[NBKT];
    __shared__ int cur[NBKT];
    __shared__ int exc[NBKT + 1];

    const int t = threadIdx.x;
    const int blk = blockIdx.x;
    const int e0 = blk * CHUNK;
    const int e1 = min(e0 + CHUNK, E);
    const int ne = e1 - e0;

    for (int i = t; i < NBKT; i += 256) cnt[i] = 0;
    __syncthreads();

    for (int i = e0 + t; i < e1; i += 256) {
        unsigned s = (unsigned)ei[i];
        unsigned d = (unsigned)ei[E + i];
        lrec[i - e0] = s | (d << 16);
        atomicAdd(&cnt[d / BSPAN], 1);
    }
    __syncthreads();

    // exclusive scan of cnt[512] by wave 0 (lane covers 8 bins)
    if (t < 64) {
        int c[8]; int s = 0;
        #pragma unroll
        for (int k = 0; k < 8; ++k) { c[k] = cnt[t * 8 + k]; s += c[k]; }
        int inc = s;
        #pragma unroll
        for (int d = 1; d < 64; d <<= 1) { int u = __shfl_up(inc, d); if (t >= d) inc += u; }
        int ex = inc - s;
        #pragma unroll
        for (int k = 0; k < 8; ++k) { exc[t * 8 + k] = ex; cur[t * 8 + k] = ex; ex += c[k]; }
        if (t == 63) exc[NBKT] = ex;
    }
    __syncthreads();

    for (int i = t; i < ne; i += 256) {
        unsigned r = lrec[i];
        unsigned d = r >> 16;
        unsigned b = d / BSPAN;
        int p = atomicAdd(&cur[b], 1);
        lsrt[p] = (r & 0xFFFFu) | ((d - b * BSPAN) << 16);
    }
    __syncthreads();

    for (int i = t; i < ne; i += 256) gout[e0 + i] = lsrt[i];       // coalesced
    for (int i = t; i < NBKT + 1; i += 256)
        goff[blk * (NBKT + 1) + i] = e0 + exc[i];
}

// ---------------- per-bucket exact CSR (device body, dynamic LDS) ----------

__device__ __forceinline__ void csr_body(
    char* smem, int bkt,
    const unsigned* __restrict__ gout, const int* __restrict__ goff,
    int* __restrict__ csrc, int2* __restrict__ rowse,
    int n, int nlb)
{
    unsigned* ltmp  = (unsigned*)smem;                          // REGS
    int* lout  = (int*)(smem + REGS * 4);                       // REGS
    int* lcnt  = (int*)(smem + 2 * REGS * 4);                   // BSPAN
    int* lbase = lcnt + BSPAN;                                  // BSPAN+1
    int* lcur  = lbase + BSPAN + 1;                             // BSPAN
    int* rg0   = lcur + BSPAN;                                  // NLBMAX
    int* rlen  = rg0 + NLBMAX;                                  // NLBMAX
    int* rbase = rlen + NLBMAX;                                 // NLBMAX+1

    const int t = threadIdx.x;
    const int node0 = bkt * BSPAN;
    if (node0 >= n) return;
    const int nn = min(BSPAN, n - node0);

    for (int i = t; i < BSPAN; i += 256) lcnt[i] = (i < nn) ? 1 : 0;  // self loop
    if (t < nlb) {
        int g0 = goff[t * (NBKT + 1) + bkt];
        int g1 = goff[t * (NBKT + 1) + bkt + 1];
        rg0[t] = g0;
        rlen[t] = g1 - g0;
    }
    __syncthreads();

    // exclusive scan of rlen[nlb<=256] by wave 0 (lane covers 4 entries)
    if (t < 64) {
        int c[4]; int s = 0;
        #pragma unroll
        for (int k = 0; k < 4; ++k) {
            int idx = t * 4 + k;
            c[k] = (idx < nlb) ? rlen[idx] : 0;
            s += c[k];
        }
        int inc = s;
        #pragma unroll
        for (int d = 1; d < 64; d <<= 1) { int u = __shfl_up(inc, d); if (t >= d) inc += u; }
        int ex = inc - s;
        #pragma unroll
        for (int k = 0; k < 4; ++k) { rbase[t * 4 + k] = ex; ex += c[k]; }
        if (t == 63) rbase[NLBMAX] = ex;
    }
    __syncthreads();

    const int tot = min(rbase[nlb], REGS - BSPAN);

    // thread-per-record gather: binary search run, copy
    for (int i = t; i < tot; i += 256) {
        int lo = 0, hi = nlb;
        while (hi - lo > 1) {
            int mid = (lo + hi) >> 1;
            if (rbase[mid] <= i) lo = mid; else hi = mid;
        }
        ltmp[i] = gout[rg0[lo] + (i - rbase[lo])];
    }
    __syncthreads();

    for (int i = t; i < tot; i += 256) atomicAdd(&lcnt[ltmp[i] >> 16], 1);
    __syncthreads();

    // exclusive scan of lcnt[98] by wave 0 (lane covers 2 bins)
    if (t < 64) {
        int b0 = t * 2, b1 = t * 2 + 1;
        int c0 = (b0 < BSPAN) ? lcnt[b0] : 0;
        int c1 = (b1 < BSPAN) ? lcnt[b1] : 0;
        int s = c0 + c1;
        int inc = s;
        #pragma unroll
        for (int d = 1; d < 64; d <<= 1) { int u = __shfl_up(inc, d); if (t >= d) inc += u; }
        int ex = inc - s;
        if (b0 < BSPAN) { lbase[b0] = ex;      lcur[b0] = ex + 1; }      // slot 0 = self
        if (b1 < BSPAN) { lbase[b1] = ex + c0; lcur[b1] = ex + c0 + 1; }
        if (t == 63) lbase[BSPAN] = inc;
    }
    __syncthreads();

    for (int i = t; i < nn; i += 256) lout[lbase[i]] = node0 + i;    // self loops
    for (int i = t; i < tot; i += 256) {
        unsigned r = ltmp[i];
        int p = atomicAdd(&lcur[r >> 16], 1);
        lout[p] = (int)(r & 0xFFFFu);
    }
    __syncthreads();

    const int gbase = bkt * REGS;
    const int total = tot + nn;
    for (int i = t; i < total; i += 256) csrc[gbase + i] = lout[i];  // coalesced
    for (int i = t; i < nn; i += 256)
        rowse[node0 + i] = make_int2(gbase + lbase[i], gbase + lbase[i + 1]);
}

// ---------------- MFMA GEMM + alpha (device body, dynamic LDS) -------------

template <int K, typename XT>
__device__ __forceinline__ void gemm_body(
    char* smem, int bx,
    const XT* __restrict__ x, const float* __restrict__ W,
    const float* __restrict__ a_src, const float* __restrict__ a_dst,
    __half* __restrict__ h16, float* __restrict__ as_, float* __restrict__ ad_, int n)
{
    constexpr int KP = K + 8;                 // row stride in halves; 2*KP % 16 == 0
    _Float16* Ah = (_Float16*)smem;           // 64 * KP
    _Float16* Wf = (_Float16*)(smem + 64 * KP * 2);  // K * 64, fragment layout

    const int t    = threadIdx.x;
    const int lane = t & 63;
    const int wv   = t >> 6;
    const int n16  = lane & 15;
    const int quad = lane >> 4;
    const int r0   = bx * 64;

    // stage W in B-fragment layout: Wf[((k>>3)*64 + c)*8 + (k&7)]
    for (int i = t; i < K * 64; i += 256) {
        int k = i >> 6, c = i & 63;
        Wf[((k >> 3) * 64 + c) * 8 + (k & 7)] = (_Float16)W[i];
    }
    // stage x rows as fp16
    if constexpr (sizeof(XT) == 4) {
        constexpr int KQ = K / 4;
        for (int i = t; i < 64 * KQ; i += 256) {
            int r = i / KQ, kq = i % KQ;
            int row = r0 + r;
            float4 v = make_float4(0.f, 0.f, 0.f, 0.f);
            if (row < n) v = ((const float4*)(x + (size_t)row * K))[kq];
            half4v hv = { (_Float16)v.x, (_Float16)v.y, (_Float16)v.z, (_Float16)v.w };
            *(half4v*)&Ah[r * KP + kq * 4] = hv;
        }
    } else {
        constexpr int KO = K / 8;
        for (int i = t; i < 64 * KO; i += 256) {
            int r = i / KO, ko = i % KO;
            int row = r0 + r;
            half8 hv = {};
            if (row < n) hv = *(const half8*)((const _Float16*)x + (size_t)row * K + ko * 8);
            *(half8*)&Ah[r * KP + ko * 8] = hv;
        }
    }
    __syncthreads();

    // preload all B fragments (block-uniform W)
    half8 bfr[K / 32][4];
    #pragma unroll
    for (int kk = 0; kk < K / 32; ++kk)
        #pragma unroll
        for (int ct = 0; ct < 4; ++ct)
            bfr[kk][ct] = *(const half8*)&Wf[((kk * 4 + quad) * 64 + ct * 16 + n16) * 8];

    f32x4 acc[4];
    #pragma unroll
    for (int ct = 0; ct < 4; ++ct) acc[ct] = (f32x4){0.f, 0.f, 0.f, 0.f};

    #pragma unroll
    for (int kk = 0; kk < K / 32; ++kk) {
        half8 a = *(const half8*)&Ah[(wv * 16 + n16) * KP + kk * 32 + quad * 8];
        #pragma unroll
        for (int ct = 0; ct < 4; ++ct)
            acc[ct] = __builtin_amdgcn_mfma_f32_16x16x32_f16(a, bfr[kk][ct], acc[ct], 0, 0, 0);
    }

    // epilogue: alpha dots off fp32 accumulators + fp16 h store
    const int rowb = r0 + wv * 16 + quad * 4;
    float asv[4], adv[4];
    #pragma unroll
    for (int ct = 0; ct < 4; ++ct) {
        asv[ct] = a_src[ct * 16 + n16];
        adv[ct] = a_dst[ct * 16 + n16];
    }
    float pa[4] = {0.f, 0.f, 0.f, 0.f}, pd[4] = {0.f, 0.f, 0.f, 0.f};
    #pragma unroll
    for (int ct = 0; ct < 4; ++ct)
        #pragma unroll
        for (int r = 0; r < 4; ++r) {
            pa[r] = fmaf(acc[ct][r], asv[ct], pa[r]);
            pd[r] = fmaf(acc[ct][r], adv[ct], pd[r]);
        }
    #pragma unroll
    for (int r = 0; r < 4; ++r) {
        #pragma unroll
        for (int d = 1; d <= 8; d <<= 1) {
            pa[r] += __shfl_xor(pa[r], d);
            pd[r] += __shfl_xor(pd[r], d);
        }
    }
    if (n16 == 0) {
        #pragma unroll
        for (int r = 0; r < 4; ++r) {
            if (rowb + r < n) { as_[rowb + r] = pa[r]; ad_[rowb + r] = pd[r]; }
        }
    }

    _Float16* hh = (_Float16*)h16;
    #pragma unroll
    for (int r = 0; r < 4; ++r) {
        if (rowb + r < n) {
            #pragma unroll
            for (int ct = 0; ct < 4; ++ct)
                hh[(size_t)(rowb + r) * 64 + ct * 16 + n16] = (_Float16)acc[ct][r];
        }
    }
}

// ---------------- fused launch 2: [csr buckets | gemm layer 1] -------------

__global__ __launch_bounds__(256) void k_csr_gemm1(
    const unsigned* __restrict__ gout, const int* __restrict__ goff,
    int* __restrict__ csrc, int2* __restrict__ rowse, int nlb,
    const float* __restrict__ x, const float* __restrict__ W1,
    const float* __restrict__ a1s, const float* __restrict__ a1d,
    __half* __restrict__ h16, float* __restrict__ as_, float* __restrict__ ad_, int n)
{
    extern __shared__ __align__(16) char smem[];
    if (blockIdx.x < NBKT)
        csr_body(smem, blockIdx.x, gout, goff, csrc, rowse, n, nlb);
    else
        gemm_body<128, float>(smem, blockIdx.x - NBKT, x, W1, a1s, a1d, h16, as_, ad_, n);
}

// ---------------- deg>32 fallback for the fused kernel (rare) --------------

__device__ __noinline__ void agg_slow_to_lds(
    int nd, int lr, int lane,
    const int2* __restrict__ rowse, const int* __restrict__ csrc,
    const __half* __restrict__ h16, const float* __restrict__ as_,
    const float* __restrict__ ad_, const float* __restrict__ b1,
    _Float16* __restrict__ Ah)
{
    const int2 se = rowse[nd];
    const int st = se.x, en = se.y;
    const float adn = ad_[nd];
    const __half* __restrict__ hp = h16 + lane;

    float m = -1e30f;
    for (int base = st; base < en; base += 64) {
        int idx = base + lane;
        if (idx < en) m = fmaxf(m, leaky(as_[csrc[idx]] + adn));
    }
    #pragma unroll
    for (int d = 32; d >= 1; d >>= 1) m = fmaxf(m, __shfl_xor(m, d));

    float a0 = 0.f, a1 = 0.f, a2 = 0.f, a3 = 0.f, dsum = 0.f;
    for (int base = st; base < en; base += 64) {
        int idx = base + lane;
        int s = 0; float w = 0.f;
        if (idx < en) {
            s = csrc[idx];
            w = __expf(leaky(as_[s] + adn) - m);
        }
        dsum += w;
        int off = s << 6;
        int wu = __float_as_uint(w);
        int cnt = min(64, en - base);
        int cr = (cnt + 3) & ~3;
        for (int j = 0; j < cr; j += 4) {
            int   o0 = RL(off, j + 0), o1 = RL(off, j + 1);
            int   o2 = RL(off, j + 2), o3 = RL(off, j + 3);
            float w0 = __uint_as_float(RL(wu, j + 0));
            float w1 = __uint_as_float(RL(wu, j + 1));
            float w2 = __uint_as_float(RL(wu, j + 2));
            float w3 = __uint_as_float(RL(wu, j + 3));
            float v0 = __half2float(hp[o0]), v1 = __half2float(hp[o1]);
            float v2 = __half2float(hp[o2]), v3 = __half2float(hp[o3]);
            a0 = fmaf(w0, v0, a0);
            a1 = fmaf(w1, v1, a1);
            a2 = fmaf(w2, v2, a2);
            a3 = fmaf(w3, v3, a3);
        }
    }
    #pragma unroll
    for (int d = 32; d >= 1; d >>= 1) dsum += __shfl_xor(dsum, d);
    float o = ((a0 + a1) + (a2 + a3)) / dsum + b1[lane];
    o = fmaxf(o, 0.f);
    Ah[lr * 72 + lane] = (_Float16)o;
}

// ---------------- fused launch 3: agg layer-1 -> MFMA layer-2 --------------
// 512 threads = 8 waves. Aggregate: 8 waves x 2 nodes x 4 iters into the
// MFMA A-tile (fp16, stride 72). MFMA phase: waves 0-3.

__global__ __launch_bounds__(512) void k_agg1_gemm2(
    const int2* __restrict__ rowse, const int* __restrict__ csrc,
    const __half* __restrict__ h16, const float* __restrict__ as_,
    const float* __restrict__ ad_, const float* __restrict__ b1,
    const float* __restrict__ W2, const float* __restrict__ a2s,
    const float* __restrict__ a2d,
    __half* __restrict__ h16b, float* __restrict__ as2_, float* __restrict__ ad2_, int n)
{
    constexpr int KP = 72;                       // 64 + 8 pad (halves)
    __shared__ __align__(16) _Float16 Ah[64 * KP];   // the MFMA A-tile
    __shared__ __align__(16) _Float16 Wf[64 * 64];
    __shared__ int2 swL[8][64];

    const int t    = threadIdx.x;
    const int lane = t & 63;
    const int wid  = t >> 6;                     // 0..7
    const int nt0  = blockIdx.x * 64;

    // stage W2 fragments (independent of the aggregate phase)
    for (int i = t; i < 64 * 64; i += 512) {
        int k = i >> 6, c = i & 63;
        Wf[((k >> 3) * 64 + c) * 8 + (k & 7)] = (_Float16)W2[i];
    }
    // zero A-tile only when the tile is partial (last block)
    if (nt0 + 64 > n) {
        for (int i = t; i < 64 * KP; i += 512) Ah[i] = (_Float16)0.f;
        __syncthreads();
    }

    // ---- aggregate phase: 4 iterations, pair of nodes per wave ----
    #pragma unroll
    for (int it = 0; it < 4; ++it) {
        const int nodeA = nt0 + (it * 8 + wid) * 2;
        if (nodeA >= n) break;

        const int half = lane >> 5;
        const int hl   = lane & 31;
        const int node = nodeA + half;
        const int ln   = node - nt0;             // local row

        const int2 se = rowse[node];
        const float adn = ad_[node];
        const int start = se.x;
        const int deg   = se.y - se.x;
        const int mdeg  = max(deg, __shfl_xor(deg, 32));

        if (mdeg <= 32) {
            // 1) s gather + publish offsets
            int s = 0;
            const bool act = hl < deg;
            if (act) s = csrc[start + hl];
            swL[wid][lane].x = s << 6;

            const int g  = (lane >> 3) & 3;
            const int fl = (lane & 7) << 3;
            const __half* __restrict__ hf = h16 + fl;
            int nit = (deg + 3) >> 2;
            nit = max(nit, __shfl_xor(nit, 32));

            // 2) issue ALL h-row loads
            const int sbase = (half << 5) + g;
            uint4 v[8];
            #pragma unroll
            for (int j = 0; j < 8; ++j) {
                if (j < nit)
                    v[j] = *(const uint4*)(hf + swL[wid][sbase + (j << 2)].x);
            }

            // 3) w chain overlaps in-flight h loads
            float e = -1e30f;
            if (act) e = leaky(as_[s] + adn);
            float w = __expf(e);
            float dsum = w;
            #pragma unroll
            for (int d = 16; d >= 1; d >>= 1) dsum += __shfl_xor(dsum, d);
            swL[wid][lane].y = __float_as_int(w);

            // 4) fma
            float af[8] = {0.f, 0.f, 0.f, 0.f, 0.f, 0.f, 0.f, 0.f};
            #pragma unroll
            for (int j = 0; j < 8; ++j) {
                if (j < nit) {
                    float wj = __int_as_float(swL[wid][sbase + (j << 2)].y);
                    unsigned uu[4] = {v[j].x, v[j].y, v[j].z, v[j].w};
                    #pragma unroll
                    for (int q = 0; q < 4; ++q) {
                        __half2 h2 = *(__half2*)&uu[q];
                        float2 f2 = __half22float2(h2);
                        af[2 * q]     = fmaf(wj, f2.x, af[2 * q]);
                        af[2 * q + 1] = fmaf(wj, f2.y, af[2 * q + 1]);
                    }
                }
            }
            #pragma unroll
            for (int q = 0; q < 8; ++q) {
                af[q] += __shfl_xor(af[q], 8);
                af[q] += __shfl_xor(af[q], 16);
            }
            if (g == 0) {                        // relu(o) -> fp16 A-tile row
                float inv = 1.f / dsum;
                float4 b0 = *(const float4*)(b1 + fl);
                float4 b4 = *(const float4*)(b1 + fl + 4);
                float o[8] = { fmaf(af[0], inv, b0.x), fmaf(af[1], inv, b0.y),
                               fmaf(af[2], inv, b0.z), fmaf(af[3], inv, b0.w),
                               fmaf(af[4], inv, b4.x), fmaf(af[5], inv, b4.y),
                               fmaf(af[6], inv, b4.z), fmaf(af[7], inv, b4.w) };
                #pragma unroll
                for (int q = 0; q < 8; ++q) o[q] = fmaxf(o[q], 0.f);
                __half2 p0 = __floats2half2_rn(o[0], o[1]);
                __half2 p1 = __floats2half2_rn(o[2], o[3]);
                __half2 p2 = __floats2half2_rn(o[4], o[5]);
                __half2 p3 = __floats2half2_rn(o[6], o[7]);
                uint4 pk = { *(unsigned*)&p0, *(unsigned*)&p1, *(unsigned*)&p2, *(unsigned*)&p3 };
                *(uint4*)&Ah[ln * KP + fl] = pk;
            }
        } else {
            agg_slow_to_lds(nodeA,     nodeA - nt0,     lane, rowse, csrc, h16, as_, ad_, b1, Ah);
            agg_slow_to_lds(nodeA + 1, nodeA + 1 - nt0, lane, rowse, csrc, h16, as_, ad_, b1, Ah);
        }
    }
    __syncthreads();

    // ---- MFMA layer-2 on the LDS tile (waves 0-3) ----
    if (wid < 4) {
        const int n16  = lane & 15;
        const int quad = lane >> 4;

        half8 bfr[2][4];
        #pragma unroll
        for (int kk = 0; kk < 2; ++kk)
            #pragma unroll
            for (int ct = 0; ct < 4; ++ct)
                bfr[kk][ct] = *(const half8*)&Wf[((kk * 4 + quad) * 64 + ct * 16 + n16) * 8];

        f32x4 acc[4];
        #pragma unroll
        for (int ct = 0; ct < 4; ++ct) acc[ct] = (f32x4){0.f, 0.f, 0.f, 0.f};

        #pragma unroll
        for (int kk = 0; kk < 2; ++kk) {
            half8 a = *(const half8*)&Ah[(wid * 16 + n16) * KP + kk * 32 + quad * 8];
            #pragma unroll
            for (int ct = 0; ct < 4; ++ct)
                acc[ct] = __builtin_amdgcn_mfma_f32_16x16x32_f16(a, bfr[kk][ct], acc[ct], 0, 0, 0);
        }

        const int rowb = nt0 + wid * 16 + quad * 4;
        float asv[4], adv[4];
        #pragma unroll
        for (int ct = 0; ct < 4; ++ct) {
            asv[ct] = a2s[ct * 16 + n16];
            adv[ct] = a2d[ct * 16 + n16];
        }
        float pa[4] = {0.f, 0.f, 0.f, 0.f}, pd[4] = {0.f, 0.f, 0.f, 0.f};
        #pragma unroll
        for (int ct = 0; ct < 4; ++ct)
            #pragma unroll
            for (int r = 0; r < 4; ++r) {
                pa[r] = fmaf(acc[ct][r], asv[ct], pa[r]);
                pd[r] = fmaf(acc[ct][r], adv[ct], pd[r]);
            }
        #pragma unroll
        for (int r = 0; r < 4; ++r) {
            #pragma unroll
            for (int d = 1; d <= 8; d <<= 1) {
                pa[r] += __shfl_xor(pa[r], d);
                pd[r] += __shfl_xor(pd[r], d);
            }
        }
        if (n16 == 0) {
            #pragma unroll
            for (int r = 0; r < 4; ++r) {
                if (rowb + r < n) { as2_[rowb + r] = pa[r]; ad2_[rowb + r] = pd[r]; }
            }
        }
        _Float16* hh = (_Float16*)h16b;
        #pragma unroll
        for (int r = 0; r < 4; ++r) {
            if (rowb + r < n) {
                #pragma unroll
                for (int ct = 0; ct < 4; ++ct)
                    hh[(size_t)(rowb + r) * 64 + ct * 16 + n16] = (_Float16)acc[ct][r];
            }
        }
    }
}

// ---------------- final aggregation (layer 2, fp32 out) --------------------

template <bool RELU>
__device__ __forceinline__ void agg_one(
    int node, int lane, int2* __restrict__ swrow,
    const int2* __restrict__ rowse,
    const int* __restrict__ csrc, const __half* __restrict__ h16,
    const float* __restrict__ as_, const float* __restrict__ ad_,
    const float* __restrict__ bias, float* __restrict__ out)
{
    const int2 se = rowse[node];
    const int start = se.x;
    const int end   = se.y;
    const int deg   = end - start;
    const float adn = ad_[node];

    if (deg <= 64) {
        int s = 0;
        if (lane < deg) s = csrc[start + lane];
        swrow[lane].x = s << 6;

        const int g  = lane >> 3;
        const int fl = (lane & 7) << 3;
        const __half* __restrict__ hf = h16 + fl;
        const int niter = (deg + 7) >> 3;

        uint4 v[8];
        #pragma unroll
        for (int j = 0; j < 8; ++j) {
            if (j < niter)
                v[j] = *(const uint4*)(hf + swrow[(j << 3) + g].x);
        }

        float e = -1e30f;
        if (lane < deg) e = leaky(as_[s] + adn);
        float w = __expf(e);
        float dsum = w;
        #pragma unroll
        for (int d = 32; d >= 1; d >>= 1) dsum += __shfl_xor(dsum, d);
        swrow[lane].y = __float_as_int(w);

        float af[8] = {0.f, 0.f, 0.f, 0.f, 0.f, 0.f, 0.f, 0.f};
        #pragma unroll
        for (int j = 0; j < 8; ++j) {
            if (j < niter) {
                float wj = __int_as_float(swrow[(j << 3) + g].y);
                unsigned uu[4] = {v[j].x, v[j].y, v[j].z, v[j].w};
                #pragma unroll
                for (int q = 0; q < 4; ++q) {
                    __half2 h2 = *(__half2*)&uu[q];
                    float2 f2 = __half22float2(h2);
                    af[2 * q]     = fmaf(wj, f2.x, af[2 * q]);
                    af[2 * q + 1] = fmaf(wj, f2.y, af[2 * q + 1]);
                }
            }
        }
        #pragma unroll
        for (int q = 0; q < 8; ++q) {
            af[q] += __shfl_xor(af[q], 8);
            af[q] += __shfl_xor(af[q], 16);
            af[q] += __shfl_xor(af[q], 32);
        }
        if (g == 0) {
            float inv = 1.f / dsum;
            float4 b0 = *(const float4*)(bias + fl);
            float4 b1v = *(const float4*)(bias + fl + 4);
            float o[8] = { fmaf(af[0], inv, b0.x), fmaf(af[1], inv, b0.y),
                           fmaf(af[2], inv, b0.z), fmaf(af[3], inv, b0.w),
                           fmaf(af[4], inv, b1v.x), fmaf(af[5], inv, b1v.y),
                           fmaf(af[6], inv, b1v.z), fmaf(af[7], inv, b1v.w) };
            if (RELU) {
                #pragma unroll
                for (int q = 0; q < 8; ++q) o[q] = fmaxf(o[q], 0.f);
            }
            float* op = out + (size_t)node * 64 + fl;
            *(float4*)op       = make_float4(o[0], o[1], o[2], o[3]);
            *(float4*)(op + 4) = make_float4(o[4], o[5], o[6], o[7]);
        }
    } else {
        const __half* __restrict__ hp = h16 + lane;
        float m = -1e30f;
        for (int base = start; base < end; base += 64) {
            int idx = base + lane;
            if (idx < end) m = fmaxf(m, leaky(as_[csrc[idx]] + adn));
        }
        #pragma unroll
        for (int d = 32; d >= 1; d >>= 1) m = fmaxf(m, __shfl_xor(m, d));

        float acc0 = 0.f, acc1 = 0.f, acc2 = 0.f, acc3 = 0.f, dsum = 0.f;
        for (int base = start; base < end; base += 64) {
            int idx = base + lane;
            int s = 0; float w = 0.f;
            if (idx < end) {
                s = csrc[idx];
                w = __expf(leaky(as_[s] + adn) - m);
            }
            dsum += w;
            int off = s << 6;
            int wu = __float_as_uint(w);
            int cnt = min(64, end - base);
            int cr = (cnt + 3) & ~3;
            for (int j = 0; j < cr; j += 4) {
                int   o0 = RL(off, j + 0), o1 = RL(off, j + 1);
                int   o2 = RL(off, j + 2), o3 = RL(off, j + 3);
                float w0 = __uint_as_float(RL(wu, j + 0));
                float w1 = __uint_as_float(RL(wu, j + 1));
                float w2 = __uint_as_float(RL(wu, j + 2));
                float w3 = __uint_as_float(RL(wu, j + 3));
                float v0 = __half2float(hp[o0]), v1 = __half2float(hp[o1]);
                float v2 = __half2float(hp[o2]), v3 = __half2float(hp[o3]);
                acc0 = fmaf(w0, v0, acc0);
                acc1 = fmaf(w1, v1, acc1);
                acc2 = fmaf(w2, v2, acc2);
                acc3 = fmaf(w3, v3, acc3);
            }
        }
        #pragma unroll
        for (int d = 32; d >= 1; d >>= 1) dsum += __shfl_xor(dsum, d);
        float acc = (acc0 + acc1) + (acc2 + acc3);
        float o = acc / dsum + bias[lane];
        if (RELU) o = fmaxf(o, 0.f);
        out[(size_t)node * 64 + lane] = o;
    }
}

template <bool RELU>
__global__ __launch_bounds__(256) void k_aggregate(
    const int2* __restrict__ rowse,
    const int* __restrict__ csrc,
    const __half* __restrict__ h16, const float* __restrict__ as_,
    const float* __restrict__ ad_, const float* __restrict__ bias,
    float* __restrict__ out, int n)
{
    __shared__ int2 swL[4][64];

    const int lane = threadIdx.x & 63;
    const int wid  = threadIdx.x >> 6;
    const int nodeA = (blockIdx.x * 4 + wid) * 2;
    if (nodeA >= n) return;

    const int half = lane >> 5;
    const int hl   = lane & 31;
    const int node = nodeA + half;

    const int2 se = rowse[node];
    const float adn = ad_[node];
    const int start = se.x;
    const int deg   = se.y - se.x;
    const int mdeg  = max(deg, __shfl_xor(deg, 32));

    if (mdeg <= 32) {
        int s = 0;
        const bool act = hl < deg;
        if (act) s = csrc[start + hl];
        swL[wid][lane].x = s << 6;

        const int g  = (lane >> 3) & 3;
        const int fl = (lane & 7) << 3;
        const __half* __restrict__ hf = h16 + fl;
        int nit = (deg + 3) >> 2;
        nit = max(nit, __shfl_xor(nit, 32));

        const int sbase = (half << 5) + g;
        uint4 v[8];
        #pragma unroll
        for (int j = 0; j < 8; ++j) {
            if (j < nit)
                v[j] = *(const uint4*)(hf + swL[wid][sbase + (j << 2)].x);
        }

        float e = -1e30f;
        if (act) e = leaky(as_[s] + adn);
        float w = __expf(e);
        float dsum = w;
        #pragma unroll
        for (int d = 16; d >= 1; d >>= 1) dsum += __shfl_xor(dsum, d);
        swL[wid][lane].y = __float_as_int(w);

        float af[8] = {0.f, 0.f, 0.f, 0.f, 0.f, 0.f, 0.f, 0.f};
        #pragma unroll
        for (int j = 0; j < 8; ++j) {
            if (j < nit) {
                float wj = __int_as_float(swL[wid][sbase + (j << 2)].y);
                unsigned uu[4] = {v[j].x, v[j].y, v[j].z, v[j].w};
                #pragma unroll
                for (int q = 0; q < 4; ++q) {
                    __half2 h2 = *(__half2*)&uu[q];
                    float2 f2 = __half22float2(h2);
                    af[2 * q]     = fmaf(wj, f2.x, af[2 * q]);
                    af[2 * q + 1] = fmaf(wj, f2.y, af[2 * q + 1]);
                }
            }
        }
        #pragma unroll
        for (int q = 0; q < 8; ++q) {
            af[q] += __shfl_xor(af[q], 8);
            af[q] += __shfl_xor(af[q], 16);
        }
        if (g == 0) {
            float inv = 1.f / dsum;
            float4 b0 = *(const float4*)(bias + fl);
            float4 b1v = *(const float4*)(bias + fl + 4);
            float o[8] = { fmaf(af[0], inv, b0.x), fmaf(af[1], inv, b0.y),
                           fmaf(af[2], inv, b0.z), fmaf(af[3], inv, b0.w),
                           fmaf(af[4], inv, b1v.x), fmaf(af[5], inv, b1v.y),
                           fmaf(af[6], inv, b1v.z), fmaf(af[7], inv, b1v.w) };
            if (RELU) {
                #pragma unroll
                for (int q = 0; q < 8; ++q) o[q] = fmaxf(o[q], 0.f);
            }
            float* op = out + (size_t)node * 64 + fl;
            *(float4*)op       = make_float4(o[0], o[1], o[2], o[3]);
            *(float4*)(op + 4) = make_float4(o[4], o[5], o[6], o[7]);
        }
    } else {
        agg_one<RELU>(nodeA,     lane, swL[wid], rowse, csrc, h16, as_, ad_, bias, out);
        agg_one<RELU>(nodeA + 1, lane, swL[wid], rowse, csrc, h16, as_, ad_, bias, out);
    }
}

// ---------------- launch ----------------

extern "C" void kernel_launch(void* const* d_in, const int* in_sizes, int n_in,
                              void* d_out, int out_size, void* d_ws, size_t ws_size,
                              hipStream_t stream) {
    const float* x   = (const float*)d_in[0];
    const int*   ei  = (const int*)  d_in[1];   // [2, E]: src row 0, dst row 1
    const float* W1  = (const float*)d_in[2];
    const float* a1s = (const float*)d_in[3];
    const float* a1d = (const float*)d_in[4];
    const float* b1  = (const float*)d_in[5];
    const float* W2  = (const float*)d_in[6];
    const float* a2s = (const float*)d_in[7];
    const float* a2d = (const float*)d_in[8];
    const float* b2  = (const float*)d_in[9];
    float* out = (float*)d_out;

    const int N_ = NNODES, E_ = NEDGES;
    const int NLB = (E_ + CHUNK - 1) / CHUNK;   // 196

    char* ws = (char*)d_ws;
    size_t off = 0;
    auto alloc = [&](size_t bytes) -> void* {
        void* p = ws + off;
        off += (bytes + 255) & ~(size_t)255;
        return p;
    };
    int*      csrc     = (int*)alloc((size_t)NBKT * REGS * 4);     // 5.24 MB
    int2*     rowse    = (int2*)alloc((size_t)N_ * 8);
    float*    as_      = (float*)alloc((size_t)N_ * 4);
    float*    ad_      = (float*)alloc((size_t)N_ * 4);
    float*    as2_     = (float*)alloc((size_t)N_ * 4);
    float*    ad2_     = (float*)alloc((size_t)N_ * 4);
    __half*   h16      = (__half*)alloc((size_t)N_ * FOUT * 2);    // 6.4 MB (layer 1)
    __half*   h16b     = (__half*)alloc((size_t)N_ * FOUT * 2);    // 6.4 MB (layer 2)
    unsigned* gout     = (unsigned*)alloc((size_t)E_ * 4);         // 3.2 MB
    int*      goff     = (int*)alloc((size_t)NLB * (NBKT + 1) * 4);

    constexpr unsigned SM_G1 = 64 * (128 + 8) * 2 + 128 * 64 * 2;  // 33792 B (>= csr carve)

    const int GB = (N_ + 63) / 64;     // 782 tiles
    const int AB = (N_ / 2 + 3) / 4;   // 6250 aggregate blocks (2 nodes/wave)

    k_localsort<<<NLB, 256, 0, stream>>>(ei, gout, goff, E_);
    k_csr_gemm1<<<NBKT + GB, 256, SM_G1, stream>>>(gout, goff, csrc, rowse, NLB,
                                                   x, W1, a1s, a1d, h16, as_, ad_, N_);
    k_agg1_gemm2<<<GB, 512, 0, stream>>>(rowse, csrc, h16, as_, ad_, b1,
                                         W2, a2s, a2d, h16b, as2_, ad2_, N_);
    k_aggregate<false><<<AB, 256, 0, stream>>>(rowse, csrc, h16b, as2_, ad2_, b2, out, N_);
}

// Round 14
// 153.894 us; speedup vs baseline: 1.0223x; 1.0222x over previous
//
#include <hip/hip_runtime.h>
#include <hip/hip_bf16.h>
#include <hip/hip_fp16.h>
#include <cstddef>

// ---------------------------------------------------------------------------
// GAT 2-layer forward. N=50000 nodes, E=800000 edges (+N self loops).
// R14: R13 with the nontemporal-store type fixed (clang ext-vector f32x4,
//      not HIP_vector_type float4). Structure = R10's split 5 launches.
// ---------------------------------------------------------------------------

#define NNODES 50000
#define NEDGES 800000
#define FOUT   64
#define NBKT   512
#define BSPAN  98       // nodes per bucket (512*98 = 50176 >= 50000)
#define CHUNK  4096     // edges per localsort block
#define REGS   2560     // csrc region stride per bucket (cap; mean ~1666)
#define NLBMAX 256      // >= number of localsort blocks (196)

__device__ __forceinline__ float leaky(float t) { return t > 0.f ? t : 0.2f * t; }
#define RL(v, j) __builtin_amdgcn_readlane((v), (j))

using half8  = __attribute__((ext_vector_type(8))) _Float16;
using half4v = __attribute__((ext_vector_type(4))) _Float16;
using f32x4  = __attribute__((ext_vector_type(4))) float;

// ---------------- stage 1: local counting sort by coarse bucket ------------

__global__ __launch_bounds__(256) void k_localsort(
    const int* __restrict__ ei, unsigned* __restrict__ gout,
    int* __restrict__ goff, int E)
{
    __shared__ unsigned lrec[CHUNK];   // s | d<<16 (both < 2^16)
    __shared__ unsigned lsrt[CHUNK];
    __shared__ int cnt[NBKT];
    __shared__ int cur[NBKT];
    __shared__ int exc[NBKT + 1];

    const int t = threadIdx.x;
    const int blk = blockIdx.x;
    const int e0 = blk * CHUNK;
    const int e1 = min(e0 + CHUNK, E);
    const int ne = e1 - e0;

    for (int i = t; i < NBKT; i += 256) cnt[i] = 0;
    __syncthreads();

    for (int i = e0 + t; i < e1; i += 256) {
        unsigned s = (unsigned)ei[i];
        unsigned d = (unsigned)ei[E + i];
        lrec[i - e0] = s | (d << 16);
        atomicAdd(&cnt[d / BSPAN], 1);
    }
    __syncthreads();

    // exclusive scan of cnt[512] by wave 0 (lane covers 8 bins)
    if (t < 64) {
        int c[8]; int s = 0;
        #pragma unroll
        for (int k = 0; k < 8; ++k) { c[k] = cnt[t * 8 + k]; s += c[k]; }
        int inc = s;
        #pragma unroll
        for (int d = 1; d < 64; d <<= 1) { int u = __shfl_up(inc, d); if (t >= d) inc += u; }
        int ex = inc - s;
        #pragma unroll
        for (int k = 0; k < 8; ++k) { exc[t * 8 + k] = ex; cur[t * 8 + k] = ex; ex += c[k]; }
        if (t == 63) exc[NBKT] = ex;
    }
    __syncthreads();

    for (int i = t; i < ne; i += 256) {
        unsigned r = lrec[i];
        unsigned d = r >> 16;
        unsigned b = d / BSPAN;
        int p = atomicAdd(&cur[b], 1);
        lsrt[p] = (r & 0xFFFFu) | ((d - b * BSPAN) << 16);
    }
    __syncthreads();

    for (int i = t; i < ne; i += 256) gout[e0 + i] = lsrt[i];       // coalesced
    for (int i = t; i < NBKT + 1; i += 256)
        goff[blk * (NBKT + 1) + i] = e0 + exc[i];
}

// ---------------- per-bucket exact CSR (device body, dynamic LDS) ----------

__device__ __forceinline__ void csr_body(
    char* smem, int bkt,
    const unsigned* __restrict__ gout, const int* __restrict__ goff,
    int* __restrict__ csrc, int2* __restrict__ rowse,
    int n, int nlb)
{
    unsigned* ltmp  = (unsigned*)smem;                          // REGS
    int* lout  = (int*)(smem + REGS * 4);                       // REGS
    int* lcnt  = (int*)(smem + 2 * REGS * 4);                   // BSPAN
    int* lbase = lcnt + BSPAN;                                  // BSPAN+1
    int* lcur  = lbase + BSPAN + 1;                             // BSPAN
    int* rg0   = lcur + BSPAN;                                  // NLBMAX
    int* rlen  = rg0 + NLBMAX;                                  // NLBMAX
    int* rbase = rlen + NLBMAX;                                 // NLBMAX+1

    const int t = threadIdx.x;
    const int node0 = bkt * BSPAN;
    if (node0 >= n) return;
    const int nn = min(BSPAN, n - node0);

    for (int i = t; i < BSPAN; i += 256) lcnt[i] = (i < nn) ? 1 : 0;  // self loop
    if (t < nlb) {
        int g0 = goff[t * (NBKT + 1) + bkt];
        int g1 = goff[t * (NBKT + 1) + bkt + 1];
        rg0[t] = g0;
        rlen[t] = g1 - g0;
    }
    __syncthreads();

    // exclusive scan of rlen[nlb<=256] by wave 0 (lane covers 4 entries)
    if (t < 64) {
        int c[4]; int s = 0;
        #pragma unroll
        for (int k = 0; k < 4; ++k) {
            int idx = t * 4 + k;
            c[k] = (idx < nlb) ? rlen[idx] : 0;
            s += c[k];
        }
        int inc = s;
        #pragma unroll
        for (int d = 1; d < 64; d <<= 1) { int u = __shfl_up(inc, d); if (t >= d) inc += u; }
        int ex = inc - s;
        #pragma unroll
        for (int k = 0; k < 4; ++k) { rbase[t * 4 + k] = ex; ex += c[k]; }
        if (t == 63) rbase[NLBMAX] = ex;
    }
    __syncthreads();

    const int tot = min(rbase[nlb], REGS - BSPAN);

    // thread-per-record gather: binary search run, copy
    for (int i = t; i < tot; i += 256) {
        int lo = 0, hi = nlb;
        while (hi - lo > 1) {
            int mid = (lo + hi) >> 1;
            if (rbase[mid] <= i) lo = mid; else hi = mid;
        }
        ltmp[i] = gout[rg0[lo] + (i - rbase[lo])];
    }
    __syncthreads();

    for (int i = t; i < tot; i += 256) atomicAdd(&lcnt[ltmp[i] >> 16], 1);
    __syncthreads();

    // exclusive scan of lcnt[98] by wave 0 (lane covers 2 bins)
    if (t < 64) {
        int b0 = t * 2, b1 = t * 2 + 1;
        int c0 = (b0 < BSPAN) ? lcnt[b0] : 0;
        int c1 = (b1 < BSPAN) ? lcnt[b1] : 0;
        int s = c0 + c1;
        int inc = s;
        #pragma unroll
        for (int d = 1; d < 64; d <<= 1) { int u = __shfl_up(inc, d); if (t >= d) inc += u; }
        int ex = inc - s;
        if (b0 < BSPAN) { lbase[b0] = ex;      lcur[b0] = ex + 1; }      // slot 0 = self
        if (b1 < BSPAN) { lbase[b1] = ex + c0; lcur[b1] = ex + c0 + 1; }
        if (t == 63) lbase[BSPAN] = inc;
    }
    __syncthreads();

    for (int i = t; i < nn; i += 256) lout[lbase[i]] = node0 + i;    // self loops
    for (int i = t; i < tot; i += 256) {
        unsigned r = ltmp[i];
        int p = atomicAdd(&lcur[r >> 16], 1);
        lout[p] = (int)(r & 0xFFFFu);
    }
    __syncthreads();

    const int gbase = bkt * REGS;
    const int total = tot + nn;
    for (int i = t; i < total; i += 256) csrc[gbase + i] = lout[i];  // coalesced
    for (int i = t; i < nn; i += 256)
        rowse[node0 + i] = make_int2(gbase + lbase[i], gbase + lbase[i + 1]);
}

// ---------------- MFMA GEMM + alpha (device body, dynamic LDS) -------------
// Block = 64 rows x 64 cols, 4 waves; wave w owns rows [w*16, w*16+16).
// A-frag: A[m=lane&15][k=quad*8+j]; C/D: col=lane&15, row=quad*4+reg.

template <int K, typename XT>
__device__ __forceinline__ void gemm_body(
    char* smem, int bx,
    const XT* __restrict__ x, const float* __restrict__ W,
    const float* __restrict__ a_src, const float* __restrict__ a_dst,
    __half* __restrict__ h16, float* __restrict__ as_, float* __restrict__ ad_, int n)
{
    constexpr int KP = K + 8;                 // row stride in halves; 2*KP % 16 == 0
    _Float16* Ah = (_Float16*)smem;           // 64 * KP
    _Float16* Wf = (_Float16*)(smem + 64 * KP * 2);  // K * 64, fragment layout

    const int t    = threadIdx.x;
    const int lane = t & 63;
    const int wv   = t >> 6;
    const int n16  = lane & 15;
    const int quad = lane >> 4;
    const int r0   = bx * 64;

    // stage W in B-fragment layout: Wf[((k>>3)*64 + c)*8 + (k&7)]
    for (int i = t; i < K * 64; i += 256) {
        int k = i >> 6, c = i & 63;
        Wf[((k >> 3) * 64 + c) * 8 + (k & 7)] = (_Float16)W[i];
    }
    // stage x rows as fp16
    if constexpr (sizeof(XT) == 4) {
        constexpr int KQ = K / 4;
        for (int i = t; i < 64 * KQ; i += 256) {
            int r = i / KQ, kq = i % KQ;
            int row = r0 + r;
            float4 v = make_float4(0.f, 0.f, 0.f, 0.f);
            if (row < n) v = ((const float4*)(x + (size_t)row * K))[kq];
            half4v hv = { (_Float16)v.x, (_Float16)v.y, (_Float16)v.z, (_Float16)v.w };
            *(half4v*)&Ah[r * KP + kq * 4] = hv;
        }
    } else {
        constexpr int KO = K / 8;
        for (int i = t; i < 64 * KO; i += 256) {
            int r = i / KO, ko = i % KO;
            int row = r0 + r;
            half8 hv = {};
            if (row < n) hv = *(const half8*)((const _Float16*)x + (size_t)row * K + ko * 8);
            *(half8*)&Ah[r * KP + ko * 8] = hv;
        }
    }
    __syncthreads();

    // preload all B fragments (block-uniform W)
    half8 bfr[K / 32][4];
    #pragma unroll
    for (int kk = 0; kk < K / 32; ++kk)
        #pragma unroll
        for (int ct = 0; ct < 4; ++ct)
            bfr[kk][ct] = *(const half8*)&Wf[((kk * 4 + quad) * 64 + ct * 16 + n16) * 8];

    f32x4 acc[4];
    #pragma unroll
    for (int ct = 0; ct < 4; ++ct) acc[ct] = (f32x4){0.f, 0.f, 0.f, 0.f};

    #pragma unroll
    for (int kk = 0; kk < K / 32; ++kk) {
        half8 a = *(const half8*)&Ah[(wv * 16 + n16) * KP + kk * 32 + quad * 8];
        #pragma unroll
        for (int ct = 0; ct < 4; ++ct)
            acc[ct] = __builtin_amdgcn_mfma_f32_16x16x32_f16(a, bfr[kk][ct], acc[ct], 0, 0, 0);
    }

    // epilogue: alpha dots off fp32 accumulators + fp16 h store
    const int rowb = r0 + wv * 16 + quad * 4;
    float asv[4], adv[4];
    #pragma unroll
    for (int ct = 0; ct < 4; ++ct) {
        asv[ct] = a_src[ct * 16 + n16];
        adv[ct] = a_dst[ct * 16 + n16];
    }
    float pa[4] = {0.f, 0.f, 0.f, 0.f}, pd[4] = {0.f, 0.f, 0.f, 0.f};
    #pragma unroll
    for (int ct = 0; ct < 4; ++ct)
        #pragma unroll
        for (int r = 0; r < 4; ++r) {
            pa[r] = fmaf(acc[ct][r], asv[ct], pa[r]);
            pd[r] = fmaf(acc[ct][r], adv[ct], pd[r]);
        }
    #pragma unroll
    for (int r = 0; r < 4; ++r) {
        #pragma unroll
        for (int d = 1; d <= 8; d <<= 1) {
            pa[r] += __shfl_xor(pa[r], d);
            pd[r] += __shfl_xor(pd[r], d);
        }
    }
    if (n16 == 0) {
        #pragma unroll
        for (int r = 0; r < 4; ++r) {
            if (rowb + r < n) { as_[rowb + r] = pa[r]; ad_[rowb + r] = pd[r]; }
        }
    }

    _Float16* hh = (_Float16*)h16;
    #pragma unroll
    for (int r = 0; r < 4; ++r) {
        if (rowb + r < n) {
            #pragma unroll
            for (int ct = 0; ct < 4; ++ct)
                hh[(size_t)(rowb + r) * 64 + ct * 16 + n16] = (_Float16)acc[ct][r];
        }
    }
}

// ---------------- fused launch 2: [csr buckets | gemm layer 1] -------------

__global__ __launch_bounds__(256) void k_csr_gemm1(
    const unsigned* __restrict__ gout, const int* __restrict__ goff,
    int* __restrict__ csrc, int2* __restrict__ rowse, int nlb,
    const float* __restrict__ x, const float* __restrict__ W1,
    const float* __restrict__ a1s, const float* __restrict__ a1d,
    __half* __restrict__ h16, float* __restrict__ as_, float* __restrict__ ad_, int n)
{
    extern __shared__ __align__(16) char smem[];
    if (blockIdx.x < NBKT)
        csr_body(smem, blockIdx.x, gout, goff, csrc, rowse, n, nlb);
    else
        gemm_body<128, float>(smem, blockIdx.x - NBKT, x, W1, a1s, a1d, h16, as_, ad_, n);
}

__global__ __launch_bounds__(256) void k_gemm2(
    const __half* __restrict__ xh, const float* __restrict__ W2,
    const float* __restrict__ a2s, const float* __restrict__ a2d,
    __half* __restrict__ h16, float* __restrict__ as_, float* __restrict__ ad_, int n)
{
    extern __shared__ __align__(16) char smem[];
    gemm_body<64, _Float16>(smem, blockIdx.x, (const _Float16*)xh, W2, a2s, a2d, h16, as_, ad_, n);
}

// ---------------- per-dst aggregation (two nodes per wave) -----------------

template <bool RELU, typename OT>
__device__ __forceinline__ void agg_one(
    int node, int lane, int2* __restrict__ swrow,
    const int2* __restrict__ rowse,
    const int* __restrict__ csrc, const __half* __restrict__ h16,
    const float* __restrict__ as_, const float* __restrict__ ad_,
    const float* __restrict__ bias, OT* __restrict__ out)
{
    const int2 se = rowse[node];
    const int start = se.x;
    const int end   = se.y;
    const int deg   = end - start;
    const float adn = ad_[node];

    if (deg <= 64) {
        // load s, publish offsets, issue h loads, THEN the w chain
        int s = 0;
        if (lane < deg) s = csrc[start + lane];
        swrow[lane].x = s << 6;

        const int g  = lane >> 3;
        const int fl = (lane & 7) << 3;
        const __half* __restrict__ hf = h16 + fl;
        const int niter = (deg + 7) >> 3;

        uint4 v[8];
        #pragma unroll
        for (int j = 0; j < 8; ++j) {
            if (j < niter)
                v[j] = *(const uint4*)(hf + swrow[(j << 3) + g].x);
        }

        float e = -1e30f;
        if (lane < deg) e = leaky(as_[s] + adn);
        float w = __expf(e);            // pad lanes: exp(-1e30)=0
        float dsum = w;
        #pragma unroll
        for (int d = 32; d >= 1; d >>= 1) dsum += __shfl_xor(dsum, d);
        swrow[lane].y = __float_as_int(w);

        float af[8] = {0.f, 0.f, 0.f, 0.f, 0.f, 0.f, 0.f, 0.f};
        #pragma unroll
        for (int j = 0; j < 8; ++j) {
            if (j < niter) {
                float wj = __int_as_float(swrow[(j << 3) + g].y);
                unsigned uu[4] = {v[j].x, v[j].y, v[j].z, v[j].w};
                #pragma unroll
                for (int q = 0; q < 4; ++q) {
                    __half2 h2 = *(__half2*)&uu[q];
                    float2 f2 = __half22float2(h2);
                    af[2 * q]     = fmaf(wj, f2.x, af[2 * q]);
                    af[2 * q + 1] = fmaf(wj, f2.y, af[2 * q + 1]);
                }
            }
        }
        #pragma unroll
        for (int q = 0; q < 8; ++q) {
            af[q] += __shfl_xor(af[q], 8);
            af[q] += __shfl_xor(af[q], 16);
            af[q] += __shfl_xor(af[q], 32);
        }
        if (g == 0) {
            float inv = 1.f / dsum;
            float4 b0 = *(const float4*)(bias + fl);
            float4 b1 = *(const float4*)(bias + fl + 4);
            float o[8] = { fmaf(af[0], inv, b0.x), fmaf(af[1], inv, b0.y),
                           fmaf(af[2], inv, b0.z), fmaf(af[3], inv, b0.w),
                           fmaf(af[4], inv, b1.x), fmaf(af[5], inv, b1.y),
                           fmaf(af[6], inv, b1.z), fmaf(af[7], inv, b1.w) };
            if (RELU) {
                #pragma unroll
                for (int q = 0; q < 8; ++q) o[q] = fmaxf(o[q], 0.f);
            }
            if constexpr (sizeof(OT) == 2) {
                __half* op = (__half*)out + (size_t)node * 64 + fl;
                __half2 p0 = __floats2half2_rn(o[0], o[1]);
                __half2 p1 = __floats2half2_rn(o[2], o[3]);
                __half2 p2 = __floats2half2_rn(o[4], o[5]);
                __half2 p3 = __floats2half2_rn(o[6], o[7]);
                uint4 pk = { *(unsigned*)&p0, *(unsigned*)&p1, *(unsigned*)&p2, *(unsigned*)&p3 };
                *(uint4*)op = pk;
            } else {
                float* op = (float*)out + (size_t)node * 64 + fl;
                f32x4 o0 = { o[0], o[1], o[2], o[3] };
                f32x4 o1 = { o[4], o[5], o[6], o[7] };
                __builtin_nontemporal_store(o0, (f32x4*)op);
                __builtin_nontemporal_store(o1, (f32x4*)(op + 4));
            }
        }
    } else {
        const __half* __restrict__ hp = h16 + lane;
        float m = -1e30f;
        for (int base = start; base < end; base += 64) {
            int idx = base + lane;
            if (idx < end) m = fmaxf(m, leaky(as_[csrc[idx]] + adn));
        }
        #pragma unroll
        for (int d = 32; d >= 1; d >>= 1) m = fmaxf(m, __shfl_xor(m, d));

        float acc0 = 0.f, acc1 = 0.f, acc2 = 0.f, acc3 = 0.f, dsum = 0.f;
        for (int base = start; base < end; base += 64) {
            int idx = base + lane;
            int s = 0; float w = 0.f;
            if (idx < end) {
                s = csrc[idx];
                w = __expf(leaky(as_[s] + adn) - m);
            }
            dsum += w;
            int off = s << 6;
            int wu = __float_as_uint(w);
            int cnt = min(64, end - base);
            int cr = (cnt + 3) & ~3;
            for (int j = 0; j < cr; j += 4) {
                int   o0 = RL(off, j + 0), o1 = RL(off, j + 1);
                int   o2 = RL(off, j + 2), o3 = RL(off, j + 3);
                float w0 = __uint_as_float(RL(wu, j + 0));
                float w1 = __uint_as_float(RL(wu, j + 1));
                float w2 = __uint_as_float(RL(wu, j + 2));
                float w3 = __uint_as_float(RL(wu, j + 3));
                float v0 = __half2float(hp[o0]), v1 = __half2float(hp[o1]);
                float v2 = __half2float(hp[o2]), v3 = __half2float(hp[o3]);
                acc0 = fmaf(w0, v0, acc0);
                acc1 = fmaf(w1, v1, acc1);
                acc2 = fmaf(w2, v2, acc2);
                acc3 = fmaf(w3, v3, acc3);
            }
        }
        #pragma unroll
        for (int d = 32; d >= 1; d >>= 1) dsum += __shfl_xor(dsum, d);
        float acc = (acc0 + acc1) + (acc2 + acc3);
        float o = acc / dsum + bias[lane];
        if (RELU) o = fmaxf(o, 0.f);
        if constexpr (sizeof(OT) == 2)
            ((__half*)out)[(size_t)node * 64 + lane] = __float2half(o);
        else
            __builtin_nontemporal_store(o, (float*)out + (size_t)node * 64 + lane);
    }
}

template <bool RELU, typename OT>
__global__ __launch_bounds__(256) void k_aggregate(
    const int2* __restrict__ rowse,
    const int* __restrict__ csrc,
    const __half* __restrict__ h16, const float* __restrict__ as_,
    const float* __restrict__ ad_, const float* __restrict__ bias,
    OT* __restrict__ out, int n)
{
    __shared__ int2 swL[4][64];

    const int lane = threadIdx.x & 63;
    const int wid  = threadIdx.x >> 6;
    const int nodeA = (blockIdx.x * 4 + wid) * 2;
    if (nodeA >= n) return;

    const int half = lane >> 5;
    const int hl   = lane & 31;
    const int node = nodeA + half;           // n is even: nodeA+1 < n

    const int2 se = rowse[node];
    const float adn = ad_[node];             // independent: issue early
    const int start = se.x;
    const int deg   = se.y - se.x;
    const int mdeg  = max(deg, __shfl_xor(deg, 32));   // wave-uniform

    if (mdeg <= 32) {
        // ---- paired fast path: 32 lanes per node ----
        int s = 0;
        const bool act = hl < deg;
        if (act) s = csrc[start + hl];
        swL[wid][lane].x = s << 6;

        const int g  = (lane >> 3) & 3;      // group within half
        const int fl = (lane & 7) << 3;      // feature octet
        const __half* __restrict__ hf = h16 + fl;
        int nit = (deg + 3) >> 2;            // 1..8
        nit = max(nit, __shfl_xor(nit, 32)); // wave-uniform

        const int sbase = (half << 5) + g;
        uint4 v[8];
        #pragma unroll
        for (int j = 0; j < 8; ++j) {
            if (j < nit)
                v[j] = *(const uint4*)(hf + swL[wid][sbase + (j << 2)].x);
        }

        float e = -1e30f;                    // exp(-1e30) = 0 for pad lanes
        if (act) e = leaky(as_[s] + adn);
        float w = __expf(e);
        float dsum = w;
        #pragma unroll
        for (int d = 16; d >= 1; d >>= 1) dsum += __shfl_xor(dsum, d);
        swL[wid][lane].y = __float_as_int(w);

        float af[8] = {0.f, 0.f, 0.f, 0.f, 0.f, 0.f, 0.f, 0.f};
        #pragma unroll
        for (int j = 0; j < 8; ++j) {
            if (j < nit) {
                float wj = __int_as_float(swL[wid][sbase + (j << 2)].y);
                unsigned uu[4] = {v[j].x, v[j].y, v[j].z, v[j].w};
                #pragma unroll
                for (int q = 0; q < 4; ++q) {
                    __half2 h2 = *(__half2*)&uu[q];
                    float2 f2 = __half22float2(h2);
                    af[2 * q]     = fmaf(wj, f2.x, af[2 * q]);
                    af[2 * q + 1] = fmaf(wj, f2.y, af[2 * q + 1]);
                }
            }
        }
        #pragma unroll
        for (int q = 0; q < 8; ++q) {
            af[q] += __shfl_xor(af[q], 8);
            af[q] += __shfl_xor(af[q], 16);
        }
        if (g == 0) {                        // lanes 0-7 (A) and 32-39 (B)
            float inv = 1.f / dsum;
            float4 b0 = *(const float4*)(bias + fl);
            float4 b1 = *(const float4*)(bias + fl + 4);
            float o[8] = { fmaf(af[0], inv, b0.x), fmaf(af[1], inv, b0.y),
                           fmaf(af[2], inv, b0.z), fmaf(af[3], inv, b0.w),
                           fmaf(af[4], inv, b1.x), fmaf(af[5], inv, b1.y),
                           fmaf(af[6], inv, b1.z), fmaf(af[7], inv, b1.w) };
            if (RELU) {
                #pragma unroll
                for (int q = 0; q < 8; ++q) o[q] = fmaxf(o[q], 0.f);
            }
            if constexpr (sizeof(OT) == 2) {
                __half* op = (__half*)out + (size_t)node * 64 + fl;
                __half2 p0 = __floats2half2_rn(o[0], o[1]);
                __half2 p1 = __floats2half2_rn(o[2], o[3]);
                __half2 p2 = __floats2half2_rn(o[4], o[5]);
                __half2 p3 = __floats2half2_rn(o[6], o[7]);
                uint4 pk = { *(unsigned*)&p0, *(unsigned*)&p1, *(unsigned*)&p2, *(unsigned*)&p3 };
                *(uint4*)op = pk;
            } else {
                float* op = (float*)out + (size_t)node * 64 + fl;
                f32x4 o0 = { o[0], o[1], o[2], o[3] };
                f32x4 o1 = { o[4], o[5], o[6], o[7] };
                __builtin_nontemporal_store(o0, (f32x4*)op);
                __builtin_nontemporal_store(o1, (f32x4*)(op + 4));
            }
        }
    } else {
        agg_one<RELU, OT>(nodeA,     lane, swL[wid], rowse, csrc, h16, as_, ad_, bias, out);
        agg_one<RELU, OT>(nodeA + 1, lane, swL[wid], rowse, csrc, h16, as_, ad_, bias, out);
    }
}

// ---------------- launch ----------------

extern "C" void kernel_launch(void* const* d_in, const int* in_sizes, int n_in,
                              void* d_out, int out_size, void* d_ws, size_t ws_size,
                              hipStream_t stream) {
    const float* x   = (const float*)d_in[0];
    const int*   ei  = (const int*)  d_in[1];   // [2, E]: src row 0, dst row 1
    const float* W1  = (const float*)d_in[2];
    const float* a1s = (const float*)d_in[3];
    const float* a1d = (const float*)d_in[4];
    const float* b1  = (const float*)d_in[5];
    const float* W2  = (const float*)d_in[6];
    const float* a2s = (const float*)d_in[7];
    const float* a2d = (const float*)d_in[8];
    const float* b2  = (const float*)d_in[9];
    float* out = (float*)d_out;

    const int N_ = NNODES, E_ = NEDGES;
    const int NLB = (E_ + CHUNK - 1) / CHUNK;   // 196

    char* ws = (char*)d_ws;
    size_t off = 0;
    auto alloc = [&](size_t bytes) -> void* {
        void* p = ws + off;
        off += (bytes + 255) & ~(size_t)255;
        return p;
    };
    int*      csrc     = (int*)alloc((size_t)NBKT * REGS * 4);     // 5.24 MB
    int2*     rowse    = (int2*)alloc((size_t)N_ * 8);
    float*    as_      = (float*)alloc((size_t)N_ * 4);
    float*    ad_      = (float*)alloc((size_t)N_ * 4);
    __half*   h16      = (__half*)alloc((size_t)N_ * FOUT * 2);    // 6.4 MB
    __half*   xr2h     = (__half*)alloc((size_t)N_ * FOUT * 2);    // 6.4 MB
    unsigned* gout     = (unsigned*)alloc((size_t)E_ * 4);         // 3.2 MB
    int*      goff     = (int*)alloc((size_t)NLB * (NBKT + 1) * 4);

    constexpr unsigned SM_G1 = 64 * (128 + 8) * 2 + 128 * 64 * 2;  // 33792 B (>= csr carve)
    constexpr unsigned SM_G2 = 64 * (64 + 8) * 2  + 64 * 64 * 2;   // 17408 B

    const int GB = (N_ + 63) / 64;     // 782 gemm blocks
    const int AB = (N_ / 2 + 3) / 4;   // 6250 aggregate blocks (2 nodes/wave)

    k_localsort<<<NLB, 256, 0, stream>>>(ei, gout, goff, E_);
    k_csr_gemm1<<<NBKT + GB, 256, SM_G1, stream>>>(gout, goff, csrc, rowse, NLB,
                                                   x, W1, a1s, a1d, h16, as_, ad_, N_);
    k_aggregate<true,  __half><<<AB, 256, 0, stream>>>(rowse, csrc, h16, as_, ad_, b1, xr2h, N_);
    k_gemm2<<<GB, 256, SM_G2, stream>>>(xr2h, W2, a2s, a2d, h16, as_, ad_, N_);
    k_aggregate<false, float ><<<AB, 256, 0, stream>>>(rowse, csrc, h16, as_, ad_, b2, out, N_);
}